// Round 13
// baseline (270.626 us; speedup 1.0000x reference)
//
#include <hip/hip_runtime.h>
#include <math.h>

#define DI __device__ __forceinline__

constexpr int B_ = 16, CLS_ = 20, C_ = 512, H_ = 4, HD_ = 128, N_ = 1024, G_ = 80, G2_ = 160, K_ = 9;
constexpr float EPS_ = 1e-5f;
constexpr float BNS_ = 0.9999950000374997f;     // 1/sqrt(1+1e-5)
constexpr float SCALE_ = 0.08838834764831845f;  // 128^-0.5
constexpr float INVSQRT2_ = 0.7071067811865475f;

typedef __attribute__((ext_vector_type(8))) short bf16x8;
typedef __attribute__((ext_vector_type(4))) float f32x4;

// ---- workspace layout (float slots) ----
constexpr long OFF_PART  = 0;                      // 2048
constexpr long OFF_EB    = 4096;                   // E bf16 [16][128][512] = 524288 slots
constexpr long OFF_EBB   = OFF_EB    + 524288;     // 1280 fp32
constexpr long OFF_KV    = OFF_EBB   + 2048;       // 16*20*1024 fp32
constexpr long OFF_AMAPT = OFF_KV    + 327680;     // 16*1024*80 fp32
constexpr long OFF_XF    = OFF_AMAPT + 1310720;
constexpr long OFF_XUB   = OFF_XF    + 1310720;    // bf16 16*1024*96 = 786432 slots
constexpr long OFF_W1BD  = OFF_XUB   + 786432;     // 16384
constexpr long OFF_FC2B  = OFF_W1BD  + 16384;      // 8192
constexpr long OFF_SQ    = OFF_FC2B  + 8192;       // 16384
constexpr long OFF_CAND  = OFF_SQ    + 16384;      // candidates float2 [16][1024][16][9] = 4718592 slots
constexpr long OFF_AOB   = OFF_CAND  + 4718592;    // aob bf16 [16][1024][512] -> 4194304 slots
constexpr long OFF_GOUTT = OFF_AOB   + 4194304;    // 1310720
constexpr long OFF_WPB   = OFF_GOUTT + 1310720;    // 131072 (proj_w bf16)
constexpr long OFF_Y     = OFF_WPB   + 131072;     // 1310720
constexpr long OFF_FC1B  = OFF_Y     + 1310720;    // fc1_w bf16 [80][96] -> 4096
constexpr long OFF_PB    = OFF_FC1B  + 4096;       // bias partials [16][8][80] -> 10240
constexpr long OFF_XCB   = OFF_PB    + 10240;      // cls-LN bf16 [16][32][512] -> 131072
constexpr long OFF_PKVB  = OFF_XCB   + 131072;     // pkv_w bf16 [1024][512] -> 262144

DI float wsum(float v){
#pragma unroll
  for(int d=1; d<64; d<<=1) v += __shfl_xor(v, d);
  return v;
}
DI unsigned short f2b(float f){
  unsigned u = __float_as_uint(f);
  unsigned r = (u + 0x7FFFu + ((u >> 16) & 1u)) >> 16;
  return (unsigned short)r;
}

#define GLOAD16(g, s) __builtin_amdgcn_global_load_lds((const __attribute__((address_space(1))) void*)(g), \
                        (__attribute__((address_space(3))) void*)(s), 16, 0, 0)

// K_pre: uniform short blocks, tiny LDS.
__global__ __launch_bounds__(256) void k_pre(const float* __restrict__ x, float* __restrict__ part,
                                             const float* __restrict__ xcls,
                                             const float* __restrict__ ncw, const float* __restrict__ ncb,
                                             unsigned short* __restrict__ xcb,
                                             const float* __restrict__ pkvw, unsigned short* __restrict__ pkvb16,
                                             const float* __restrict__ projw, unsigned short* __restrict__ wpb,
                                             const float* __restrict__ mrw, const float* __restrict__ fc2w,
                                             const float* __restrict__ fc1w,
                                             unsigned short* __restrict__ w1bd, unsigned short* __restrict__ fc2b16,
                                             unsigned short* __restrict__ fc1b16){
  __shared__ float rs[4], rss[4];
  int blk = blockIdx.x, t = threadIdx.x;
  if(blk < 1024){
    const float4* xp = (const float4*)x;
    long base4 = (long)blk * 2048;
    float s = 0.f, ss = 0.f;
#pragma unroll
    for(int j=0;j<8;++j){
      float4 v = xp[base4 + t + 256*j];
      s  += v.x + v.y + v.z + v.w;
      ss += v.x*v.x + v.y*v.y + v.z*v.z + v.w*v.w;
    }
    s = wsum(s); ss = wsum(ss);
    int wv = t >> 6;
    if((t & 63) == 0){ rs[wv] = s; rss[wv] = ss; }
    __syncthreads();
    if(t == 0){
      part[blk*2]   = rs[0]+rs[1]+rs[2]+rs[3];
      part[blk*2+1] = rss[0]+rss[1]+rss[2]+rss[3];
    }
    return;
  }
  if(blk < 1040){
    int b = blk - 1024;
    int wv = t >> 6, l = t & 63;
    for(int cls = wv; cls < 32; cls += 4){
      unsigned short* orow = xcb + ((long)b*32 + cls)*512;
      if(cls < CLS_){
        const float* xr = xcls + ((long)b*CLS_ + cls) * C_;
        float vals[8];
        float s = 0.f, ss = 0.f;
#pragma unroll
        for(int j=0;j<8;++j){ float v = xr[l + 64*j]; vals[j] = v; s += v; ss += v*v; }
        s = wsum(s); ss = wsum(ss);
        float m = s / (float)C_;
        float var = ss / (float)C_ - m*m;
        float inv = 1.0f / sqrtf(var + EPS_);
#pragma unroll
        for(int j=0;j<8;++j){
          int c = l + 64*j;
          orow[c] = f2b((vals[j]-m)*inv*ncw[c] + ncb[c]);
        }
      } else {
#pragma unroll
        for(int j=0;j<8;++j) orow[l + 64*j] = 0;
      }
    }
    return;
  }
  if(blk < 1296){
    long i = (long)(blk - 1040)*256 + t;
    float4 v = ((const float4*)projw)[i];
    uint2 o;
    o.x = (unsigned)f2b(v.x) | ((unsigned)f2b(v.y) << 16);
    o.y = (unsigned)f2b(v.z) | ((unsigned)f2b(v.w) << 16);
    ((uint2*)wpb)[i] = o;
    return;
  }
  if(blk < 1808){
    long i = (long)(blk - 1296)*256 + t;
    float4 v = ((const float4*)pkvw)[i];
    uint2 o;
    o.x = (unsigned)f2b(v.x) | ((unsigned)f2b(v.y) << 16);
    o.y = (unsigned)f2b(v.z) | ((unsigned)f2b(v.w) << 16);
    ((uint2*)pkvb16)[i] = o;
    return;
  }
  int row = blk - 1808;
  if(row < 160){
    if(t < 160){
      unsigned short v = 0;
      if(t/40 == row/40) v = f2b(mrw[row*40 + (t % 40)]);
      w1bd[row*160 + t] = v;
    }
  } else if(row < 240){
    if(t < 160) fc2b16[(row-160)*160 + t] = f2b(fc2w[(long)(row-160)*160 + t]);
  } else if(row < 320){
    int r = row - 240;
    if(t < 96) fc1b16[r*96 + t] = (t < G_) ? f2b(fc1w[(long)r*G_ + t]) : (unsigned short)0;
  }
}

// kv projection via MFMA
__global__ __launch_bounds__(256) void k_kv_mfma(const unsigned short* __restrict__ xcb,
                                                 const unsigned short* __restrict__ pkvb16,
                                                 const float* __restrict__ pkvb,
                                                 float* __restrict__ kv){
  __shared__ unsigned short Al[4096];
  __shared__ unsigned short Bl[1024];
  int b = blockIdx.x >> 3, o0 = (blockIdx.x & 7)*128;
  int t = threadIdx.x, w = t >> 6, l = t & 63;
  f32x4 acc[2][2] = {};
  const unsigned short* At = pkvb16 + (long)(o0 + w*16 + (l>>2))*512 + (l&3)*8;
  const unsigned short* Bt = xcb + ((long)b*32 + w*16 + (l>>2))*512 + (l&3)*8;
  int kq = (l >> 4)*8;
  for(int k0 = 0; k0 < 512; k0 += 32){
    if(k0) __syncthreads();
    GLOAD16(At + k0,          &Al[w*512]);
    GLOAD16(At + 64*512 + k0, &Al[2048 + w*512]);
    if(w < 2) GLOAD16(Bt + k0, &Bl[w*512]);
    __syncthreads();
    bf16x8 af[2], bfr[2];
#pragma unroll
    for(int mi=0; mi<2; ++mi) af[mi]  = *(const bf16x8*)&Al[(w*32 + mi*16 + (l & 15))*32 + kq];
#pragma unroll
    for(int ni=0; ni<2; ++ni) bfr[ni] = *(const bf16x8*)&Bl[(ni*16 + (l & 15))*32 + kq];
#pragma unroll
    for(int mi=0; mi<2; ++mi)
#pragma unroll
      for(int ni=0; ni<2; ++ni)
        acc[mi][ni] = __builtin_amdgcn_mfma_f32_16x16x32_bf16(af[mi], bfr[ni], acc[mi][ni], 0, 0, 0);
  }
  int r0 = (l >> 4)*4;
#pragma unroll
  for(int mi=0; mi<2; ++mi){
#pragma unroll
    for(int r=0; r<4; ++r){
      int o = o0 + w*32 + mi*16 + r0 + r;
      float bi = pkvb[o];
#pragma unroll
      for(int ni=0; ni<2; ++ni){
        int cls = ni*16 + (l & 15);
        if(cls < CLS_) kv[((long)b*CLS_ + cls)*1024 + o] = acc[mi][ni][r] + bi;
      }
    }
  }
}

// E prep: inline batch stats; folds patch-norm affine into E' and bias partials.
__global__ __launch_bounds__(256) void k_eprep(const float* __restrict__ kv, const float* __restrict__ pqw,
                                               const float* __restrict__ pqb, const float* __restrict__ partbuf,
                                               const float* __restrict__ nw, const float* __restrict__ nbv,
                                               unsigned short* __restrict__ Eb, float* __restrict__ ebb,
                                               float* __restrict__ pb){
  int b = blockIdx.x, hh = blockIdx.y, cch = blockIdx.z, t = threadIdx.x;
  if(hh == 4){
    if(cch == 0){
      unsigned* z = (unsigned*)(Eb + ((long)b*128 + 80)*512);
      for(int i=t; i<12288; i+=256) z[i] = 0;
    }
    return;
  }
  __shared__ float sst[2];
  __shared__ float key[CLS_][HD_];
  __shared__ float part[4][CLS_][64];
  if(t < 64){
    float s  = partbuf[(b*64+t)*2];
    float ss = partbuf[(b*64+t)*2+1];
    s = wsum(s); ss = wsum(ss);
    if(t == 0){
      const float cnt = (float)(C_ * N_);
      float m = s / cnt;
      sst[0] = m;
      sst[1] = 1.0f / sqrtf(ss / cnt - m*m + EPS_);
    }
  }
  int h = hh, c0 = cch*64;
  for(int i=t; i<CLS_*HD_; i+=256){
    int cls = i >> 7, d = i & 127;
    key[cls][d] = kv[((long)b*CLS_+cls)*1024 + h*HD_ + d];
  }
  __syncthreads();
  float m = sst[0], inv = sst[1];
  int c = t & 63, ds = t >> 6;
  float acc[CLS_] = {};
  const float* wp = pqw + ((long)(h*HD_ + ds*32))*C_ + c0 + c;
#pragma unroll 8
  for(int di=0; di<32; ++di){
    float wv = wp[(long)di*C_];
#pragma unroll
    for(int cls=0; cls<CLS_; ++cls) acc[cls] += key[cls][ds*32+di]*wv;
  }
#pragma unroll
  for(int cls=0; cls<CLS_; ++cls) part[ds][cls][c] = acc[cls];
  __syncthreads();
  for(int i=t; i<CLS_*64; i+=256){
    int cls = i >> 6, cc = i & 63;
    float v = (part[0][cls][cc]+part[1][cls][cc]+part[2][cls][cc]+part[3][cls][cc]) * SCALE_;
    int cg = c0 + cc;
    float a = inv * nw[cg];
    float bbv = nbv[cg] - m*a;
    Eb[((long)b*128 + h*CLS_ + cls)*512 + cg] = f2b(v*a);
    part[0][cls][cc] = v*bbv;
  }
  __syncthreads();
  if(t < CLS_){
    float s = 0.f;
    for(int cc=0; cc<64; ++cc) s += part[0][t][cc];
    pb[((long)b*8 + cch)*G_ + h*CLS_ + t] = s;
  }
  if(cch == 0 && t >= 64 && t < 64 + CLS_){
    int tt = t - 64;
    float bacc = 0.f;
    for(int d=0; d<HD_; ++d) bacc += key[tt][d]*pqb[h*HD_+d];
    ebb[b*G_ + h*CLS_ + tt] = bacc*SCALE_;
  }
}

// amap GEMM + fused fc1
__global__ __launch_bounds__(256) void k_amap_fc1(const unsigned short* __restrict__ Eb,
                                                  const float* __restrict__ xp,
                                                  const float* __restrict__ ebb,
                                                  const float* __restrict__ pb,
                                                  const unsigned short* __restrict__ w1b,
                                                  const float* __restrict__ f1bias,
                                                  const float* __restrict__ g1, const float* __restrict__ b1,
                                                  float* __restrict__ amapT,
                                                  float* __restrict__ xf, unsigned short* __restrict__ xub,
                                                  float* __restrict__ sq){
  __shared__ unsigned short Xl[64*520];
  __shared__ unsigned short Bgl[4096];
  unsigned short* A1 = Xl;
  int b = blockIdx.y, n0 = blockIdx.x*64;
  int t = threadIdx.x, w = t >> 6, l = t & 63;
  int wr = w >> 1, wc = w & 1;
  {
    int nb = t & 7, cl = t >> 3;
    const float* xb = xp + (long)b*C_*N_ + n0 + nb*8;
#pragma unroll 4
    for(int pass=0; pass<16; ++pass){
      int c = pass*32 + cl;
      const float* src = xb + (long)c*N_;
      float4 v0 = *(const float4*)src;
      float4 v1 = *(const float4*)(src+4);
      int base = (nb*8)*520 + c;
      Xl[base         ] = f2b(v0.x);
      Xl[base + 520   ] = f2b(v0.y);
      Xl[base + 520*2 ] = f2b(v0.z);
      Xl[base + 520*3 ] = f2b(v0.w);
      Xl[base + 520*4 ] = f2b(v1.x);
      Xl[base + 520*5 ] = f2b(v1.y);
      Xl[base + 520*6 ] = f2b(v1.z);
      Xl[base + 520*7 ] = f2b(v1.w);
    }
  }
  __syncthreads();
  f32x4 acc[2][4] = {};
  const unsigned short* Bt = Eb + ((long)b*128 + w*16 + (l>>2))*512 + (l&3)*8;
  int ra = wr*32 + (l & 15);
  int rb = wc*64 + (l & 15);
  int kq = (l >> 4) * 8;
  for(int k0 = 0; k0 < 512; k0 += 32){
    if(k0) __syncthreads();
    GLOAD16(Bt + k0,          &Bgl[w*512]);
    GLOAD16(Bt + 64*512 + k0, &Bgl[2048 + w*512]);
    __syncthreads();
    bf16x8 af[2], bfr[4];
#pragma unroll
    for(int rt=0; rt<2; ++rt) af[rt]  = *(const bf16x8*)&Xl[(ra + rt*16)*520 + k0 + kq];
#pragma unroll
    for(int ct=0; ct<4; ++ct) bfr[ct] = *(const bf16x8*)&Bgl[(rb + ct*16)*32 + kq];
#pragma unroll
    for(int rt=0; rt<2; ++rt)
#pragma unroll
      for(int ct=0; ct<4; ++ct)
        acc[rt][ct] = __builtin_amdgcn_mfma_f32_16x16x32_bf16(af[rt], bfr[ct], acc[rt][ct], 0, 0, 0);
  }
  float bias4[4];
#pragma unroll
  for(int ct=0; ct<4; ++ct){
    int g = wc*64 + ct*16 + (l & 15);
    float bi = 0.f;
    if(g < G_){
      bi = ebb[b*G_ + g];
#pragma unroll
      for(int cc=0; cc<8; ++cc) bi += pb[((long)b*8 + cc)*G_ + g];
    }
    bias4[ct] = bi;
  }
  __syncthreads();
  int r0 = (l >> 4)*4;
#pragma unroll
  for(int rt=0; rt<2; ++rt){
#pragma unroll
    for(int r=0; r<4; ++r){
      int lrow = wr*32 + rt*16 + r0 + r;
      long rowb = ((long)b*N_ + n0 + lrow)*G_;
#pragma unroll
      for(int ct=0; ct<4; ++ct){
        int g = wc*64 + ct*16 + (l & 15);
        if(g < G_){
          float val = acc[rt][ct][r] + bias4[ct];
          amapT[rowb + g] = val;
          A1[lrow*96 + g] = f2b(val);
        } else if(g < 96){
          A1[lrow*96 + g] = 0;
        }
      }
    }
  }
  __syncthreads();
  int lr = l & 15, lk = l >> 4;
  bf16x8 ay[3];
  const unsigned short* arow = &A1[(w*16 + lr)*96 + lk*8];
#pragma unroll
  for(int ks=0; ks<3; ++ks) ay[ks] = *(const bf16x8*)&arow[ks*32];
  f32x4 acc5[5] = {};
  const unsigned short* wrow = w1b + (long)lr*96 + lk*8;
#pragma unroll
  for(int ks=0; ks<3; ++ks){
#pragma unroll
    for(int ct=0; ct<5; ++ct){
      bf16x8 bw = *(const bf16x8*)&wrow[ct*16*96 + ks*32];
      acc5[ct] = __builtin_amdgcn_mfma_f32_16x16x32_bf16(ay[ks], bw, acc5[ct], 0, 0, 0);
    }
  }
  float v[5][4];
  float ssq[4] = {0.f,0.f,0.f,0.f};
#pragma unroll
  for(int ct=0; ct<5; ++ct){
    int o = ct*16 + lr;
    float bi = f1bias[o], ga = g1[o]*BNS_, bb = b1[o];
#pragma unroll
    for(int i=0;i<4;++i){
      float vv = (acc5[ct][i] + bi)*ga + bb;
      v[ct][i] = vv;
      ssq[i] += vv*vv;
    }
  }
#pragma unroll
  for(int d=1; d<16; d<<=1){
#pragma unroll
    for(int i=0;i<4;++i) ssq[i] += __shfl_xor(ssq[i], d);
  }
  long row0g = (long)b*N_ + n0 + w*16;
#pragma unroll
  for(int i=0;i<4;++i){
    long row = row0g + lk*4 + i;
    float invn = 1.0f / fmaxf(sqrtf(ssq[i]), 1e-12f);
#pragma unroll
    for(int ct=0; ct<5; ++ct){
      int o = ct*16 + lr;
      xf[row*G_ + o] = v[ct][i];
      xub[row*96 + o] = f2b(v[ct][i]*invn);
    }
    xub[row*96 + 80 + lr] = 0;
    if(lr == 0) sq[row] = ssq[i]*invn*invn;
  }
}

// MFMA GEMM: Out[b][o][n] = sum_c Wb[o][c]*Xb[b][n][c] + bias[o] (+Res)
template<bool RES>
__global__ __launch_bounds__(256) void k_gemm_mfma(const unsigned short* __restrict__ Wb,
                                                   const unsigned short* __restrict__ Xb,
                                                   const float* __restrict__ bias,
                                                   const float* __restrict__ Res,
                                                   float* __restrict__ Out){
  __shared__ unsigned short Al[4096];
  __shared__ unsigned short Bl[4096];
  int b = blockIdx.z;
  int o0 = blockIdx.y*128, n0 = blockIdx.x*128;
  int t = threadIdx.x, w = t >> 6, l = t & 63;
  int wr = w >> 1, wc = w & 1;
  f32x4 acc[4][4] = {};
  const unsigned short* Wt = Wb + (long)(o0 + w*16 + (l>>2))*512 + (l&3)*8;
  const unsigned short* Xt = Xb + ((long)b*N_ + n0 + w*16 + (l>>2))*512 + (l&3)*8;
  int ra = wr*64 + (l & 15);
  int rb = wc*64 + (l & 15);
  int kq = (l >> 4) * 8;
  for(int k0 = 0; k0 < 512; k0 += 32){
    if(k0) __syncthreads();
    GLOAD16(Wt + k0,            &Al[w*512]);
    GLOAD16(Wt + 64*512 + k0,   &Al[2048 + w*512]);
    GLOAD16(Xt + k0,            &Bl[w*512]);
    GLOAD16(Xt + 64*512 + k0,   &Bl[2048 + w*512]);
    __syncthreads();
    bf16x8 af[4], bfr[4];
#pragma unroll
    for(int i=0;i<4;++i){
      af[i]  = *(const bf16x8*)&Al[(ra + i*16)*32 + kq];
      bfr[i] = *(const bf16x8*)&Bl[(rb + i*16)*32 + kq];
    }
#pragma unroll
    for(int mi=0; mi<4; ++mi)
#pragma unroll
      for(int ni=0; ni<4; ++ni)
        acc[mi][ni] = __builtin_amdgcn_mfma_f32_16x16x32_bf16(af[mi], bfr[ni], acc[mi][ni], 0, 0, 0);
  }
  long obase = ((long)b*C_ + o0 + wr*64)*N_ + n0 + wc*64 + (l & 15);
  int r0 = (l >> 4) * 4;
#pragma unroll
  for(int mi=0; mi<4; ++mi){
#pragma unroll
    for(int r=0; r<4; ++r){
      int row = mi*16 + r0 + r;
      float bi = bias[o0 + wr*64 + row];
#pragma unroll
      for(int ni=0; ni<4; ++ni){
        long oi = obase + (long)row*N_ + ni*16;
        float v = acc[mi][ni][r] + bi;
        if(RES) v += Res[oi];
        Out[oi] = v;
      }
    }
  }
}

// neg_d via bf16 MFMA + in-register per-half-tile top-9 candidates (no negd matrix to HBM)
__global__ __launch_bounds__(256) void k_negd_cand(const unsigned short* __restrict__ xub,
                                                   const float* __restrict__ sq,
                                                   float2* __restrict__ cand){
  __shared__ unsigned short Al[128*96];
  __shared__ unsigned short Bl[128*96];
  int b = blockIdx.z;
  int n0 = blockIdx.y*128, m0 = blockIdx.x*128;
  int t = threadIdx.x, w = t >> 6, l = t & 63;
  int wr = w >> 1, wc = w & 1;
  const unsigned short* gA = xub + ((long)b*N_ + n0)*96;
  const unsigned short* gB = xub + ((long)b*N_ + m0)*96;
#pragma unroll
  for(int rd=0; rd<6; ++rd){
    int chunk = rd*4 + w;
    GLOAD16(gA + chunk*512 + l*8, &Al[chunk*512]);
    GLOAD16(gB + chunk*512 + l*8, &Bl[chunk*512]);
  }
  __syncthreads();
  f32x4 acc[4][4] = {};
  int ra = wr*64 + (l & 15);
  int rb = wc*64 + (l & 15);
#pragma unroll
  for(int ks=0; ks<3; ++ks){
    int kq = ks*32 + (l >> 4)*8;
    bf16x8 af[4], bfr[4];
#pragma unroll
    for(int i=0;i<4;++i){
      af[i]  = *(const bf16x8*)&Al[(ra + i*16)*96 + kq];
      bfr[i] = *(const bf16x8*)&Bl[(rb + i*16)*96 + kq];
    }
#pragma unroll
    for(int mi=0; mi<4; ++mi)
#pragma unroll
      for(int ni=0; ni<4; ++ni)
        acc[mi][ni] = __builtin_amdgcn_mfma_f32_16x16x32_bf16(af[mi], bfr[ni], acc[mi][ni], 0, 0, 0);
  }
  // per-row top-9 over this wave's 64 columns (16 lanes x 4 regs), emit (key, idx)
  int lk = l >> 4, lm = l & 15;
  int mbase = m0 + wc*64 + lm;
  const float* sqb = sq + (long)b*N_;
  float smv[4];
#pragma unroll
  for(int ni=0; ni<4; ++ni) smv[ni] = sqb[m0 + wc*64 + ni*16 + lm];
  int ht = blockIdx.x*2 + wc;
#pragma unroll
  for(int mi=0; mi<4; ++mi){
#pragma unroll
    for(int r=0; r<4; ++r){
      int n = n0 + wr*64 + mi*16 + lk*4 + r;
      float sn = sqb[n];
      float key[4];
#pragma unroll
      for(int ni=0; ni<4; ++ni) key[ni] = 2.f*acc[mi][ni][r] - sn - smv[ni];
      long cbase = (((long)b*N_ + n)*16 + ht)*9;
#pragma unroll
      for(int p=0; p<K_; ++p){
        float bv = key[0]; int bj = 0;
#pragma unroll
        for(int j=1;j<4;++j) if(key[j] > bv){ bv = key[j]; bj = j; }
        int bm = mbase + bj*16;
#pragma unroll
        for(int d=1; d<16; d<<=1){
          float ov = __shfl_xor(bv, d);
          int   om = __shfl_xor(bm, d);
          if(ov > bv || (ov == bv && om < bm)){ bv = ov; bm = om; }
        }
        if(lm == p){
          float2 cd; cd.x = bv; cd.y = __int_as_float(bm);
          cand[cbase + p] = cd;
        }
#pragma unroll
        for(int j=0;j<4;++j) if(bm == mbase + j*16) key[j] = -INFINITY;
      }
    }
  }
}

// merge 144 candidates -> global top-9 -> neighbor-max -> y bf16. one wave per row.
__global__ __launch_bounds__(256) void k_merge_y(const float2* __restrict__ cand, const float* __restrict__ xf,
                                                 unsigned short* __restrict__ y){
  int t = threadIdx.x, wv = t >> 6, l = t & 63;
  long r = (long)blockIdx.x*4 + wv;
  long b = r >> 10;
  const float2* cr = cand + r*144;
  float cv[3]; int ci[3];
  {
    float2 c0 = cr[l];        cv[0] = c0.x; ci[0] = __float_as_int(c0.y);
    float2 c1 = cr[l + 64];   cv[1] = c1.x; ci[1] = __float_as_int(c1.y);
    if(l < 16){ float2 c2 = cr[l + 128]; cv[2] = c2.x; ci[2] = __float_as_int(c2.y); }
    else      { cv[2] = -INFINITY; ci[2] = 0x7FFFFFFF; }
  }
  int nbs[K_];
#pragma unroll
  for(int p=0; p<K_; ++p){
    float bv = cv[0]; int bm = ci[0];
    if(cv[1] > bv || (cv[1] == bv && ci[1] < bm)){ bv = cv[1]; bm = ci[1]; }
    if(cv[2] > bv || (cv[2] == bv && ci[2] < bm)){ bv = cv[2]; bm = ci[2]; }
#pragma unroll
    for(int d=1; d<64; d<<=1){
      float ov = __shfl_xor(bv, d);
      int   om = __shfl_xor(bm, d);
      if(ov > bv || (ov == bv && om < bm)){ bv = ov; bm = om; }
    }
    nbs[p] = bm;
#pragma unroll
    for(int j=0;j<3;++j) if(ci[j] == bm) cv[j] = -INFINITY;
  }
  const float* frow = xf + r*G_;
  int o2s = (l < 16) ? (64 + l) : 0;
  float f0 = frow[l];
  float f1 = frow[o2s];
  float m0 = -INFINITY, m1 = -INFINITY;
#pragma unroll
  for(int k=0;k<K_;++k){
    const float* nr = xf + ((long)b*N_ + nbs[k])*G_;
    m0 = fmaxf(m0, nr[l]);
    m1 = fmaxf(m1, nr[o2s]);
  }
  unsigned short* yr = y + r*G2_;
  ushort2 u0; u0.x = f2b(f0); u0.y = f2b(m0 - f0);
  *(ushort2*)&yr[2*l] = u0;
  if(l < 16){
    ushort2 u1; u1.x = f2b(f1); u1.y = f2b(m1 - f1);
    *(ushort2*)&yr[128 + 2*l] = u1;
  }
}

// MFMA mixer + bn2 + gelu + fc2 + bn3 + amap -> goutT
__global__ __launch_bounds__(256) void k_mixer_mfma(const unsigned short* __restrict__ y,
                                                    const unsigned short* __restrict__ w1bd,
                                                    const float* __restrict__ mrb,
                                                    const float* __restrict__ g2, const float* __restrict__ b2,
                                                    const unsigned short* __restrict__ fc2b16,
                                                    const float* __restrict__ fc2bias,
                                                    const float* __restrict__ g3, const float* __restrict__ b3,
                                                    const float* __restrict__ amapT, float* __restrict__ goutT){
  __shared__ unsigned short zl[4][16][G2_];
  int t = threadIdx.x, w = t >> 6, l = t & 63;
  long row0 = ((long)blockIdx.x*4 + w)*16;
  int lr = l & 15, lk = l >> 4;
  bf16x8 ay[5];
  const unsigned short* yrow = y + (row0 + lr)*G2_ + lk*8;
#pragma unroll
  for(int ks=0; ks<5; ++ks) ay[ks] = *(const bf16x8*)&yrow[ks*32];
  f32x4 accz[10] = {};
  const unsigned short* wb = w1bd + (long)lr*G2_ + lk*8;
#pragma unroll
  for(int ks=0; ks<5; ++ks){
#pragma unroll
    for(int ct=0; ct<10; ++ct){
      bf16x8 bw = *(const bf16x8*)&wb[ct*16*G2_ + ks*32];
      accz[ct] = __builtin_amdgcn_mfma_f32_16x16x32_bf16(ay[ks], bw, accz[ct], 0, 0, 0);
    }
  }
#pragma unroll
  for(int ct=0; ct<10; ++ct){
    int o = ct*16 + lr;
    float bi = mrb[o], ga = g2[o]*BNS_, bb = b2[o];
#pragma unroll
    for(int i=0;i<4;++i){
      float v = (accz[ct][i] + bi)*ga + bb;
      float zz = v * 0.5f * (1.0f + erff(v * INVSQRT2_));
      zl[w][lk*4 + i][o] = f2b(zz);
    }
  }
  __syncthreads();
  bf16x8 az[5];
#pragma unroll
  for(int ks=0; ks<5; ++ks) az[ks] = *(const bf16x8*)&zl[w][lr][ks*32 + lk*8];
  f32x4 acc2[5] = {};
  const unsigned short* fb = fc2b16 + (long)lr*G2_ + lk*8;
#pragma unroll
  for(int ks=0; ks<5; ++ks){
#pragma unroll
    for(int ct=0; ct<5; ++ct){
      bf16x8 bw = *(const bf16x8*)&fb[ct*16*G2_ + ks*32];
      acc2[ct] = __builtin_amdgcn_mfma_f32_16x16x32_bf16(az[ks], bw, acc2[ct], 0, 0, 0);
    }
  }
#pragma unroll
  for(int ct=0; ct<5; ++ct){
    int o = ct*16 + lr;
    float bi = fc2bias[o], ga = g3[o]*BNS_, bb = b3[o];
#pragma unroll
    for(int i=0;i<4;++i){
      long row = row0 + lk*4 + i;
      float v = (acc2[ct][i] + bi)*ga + bb + amapT[row*G_ + o];
      goutT[row*G_ + o] = v;
    }
  }
}

// per-thread softmax + MFMA PV -> bf16 aob[b][n][c]
__global__ __launch_bounds__(256) void k_softmax_pv(const float* __restrict__ goutT, const float* __restrict__ kv,
                                                    unsigned short* __restrict__ aob){
  int bh = blockIdx.x; int b = bh >> 2, h = bh & 3;
  int n0 = blockIdx.y * 64;
  __shared__ unsigned short Vt[128*32];
  __shared__ unsigned short Pl[64*40];
  __shared__ unsigned short Os[64*132];
  int t = threadIdx.x, w = t >> 6, l = t & 63;
  if(t < 128){
    int d = t;
    const float* vb = kv + ((long)b*CLS_)*1024 + C_ + h*HD_ + d;
#pragma unroll
    for(int cls=0; cls<CLS_; ++cls) Vt[d*32+cls] = f2b(vb[(long)cls*1024]);
#pragma unroll
    for(int cls=CLS_; cls<32; ++cls) Vt[d*32+cls] = 0;
  }
  if(t < 64){
    int n = n0 + t;
    const float* gr = goutT + ((long)b*N_ + n)*G_ + h*CLS_;
    float x[CLS_];
    float mx = -INFINITY;
#pragma unroll
    for(int cls=0; cls<CLS_; ++cls){ x[cls] = gr[cls]; mx = fmaxf(mx, x[cls]); }
    float s = 0.f;
#pragma unroll
    for(int cls=0; cls<CLS_; ++cls){ x[cls] = expf(x[cls]-mx); s += x[cls]; }
    float inv = 1.0f / s;
#pragma unroll
    for(int cls=0; cls<CLS_; ++cls) Pl[t*40+cls] = f2b(x[cls]*inv);
#pragma unroll
    for(int cls=CLS_; cls<32; ++cls) Pl[t*40+cls] = 0;
  }
  __syncthreads();
  int lr = l & 15, kq = (l >> 4)*8;
  f32x4 acc[4][2] = {};
  bf16x8 af[4], bf2[2];
#pragma unroll
  for(int rt=0; rt<4; ++rt) af[rt] = *(const bf16x8*)&Pl[(rt*16+lr)*40 + kq];
#pragma unroll
  for(int ci=0; ci<2; ++ci) bf2[ci] = *(const bf16x8*)&Vt[((2*w+ci)*16+lr)*32 + kq];
#pragma unroll
  for(int rt=0; rt<4; ++rt)
#pragma unroll
    for(int ci=0; ci<2; ++ci)
      acc[rt][ci] = __builtin_amdgcn_mfma_f32_16x16x32_bf16(af[rt], bf2[ci], acc[rt][ci], 0, 0, 0);
  int r0 = (l >> 4)*4;
#pragma unroll
  for(int rt=0; rt<4; ++rt)
#pragma unroll
    for(int ci=0; ci<2; ++ci)
#pragma unroll
      for(int i=0; i<4; ++i)
        Os[(rt*16 + r0 + i)*132 + (2*w+ci)*16 + lr] = f2b(acc[rt][ci][i]);
  __syncthreads();
  unsigned short* ob = aob + ((long)b*N_ + n0)*C_ + h*HD_;
#pragma unroll
  for(int j=0; j<8; ++j){
    int idx = t + 256*j;
    int row = idx >> 5, ch = idx & 31;
    *(ushort4*)&ob[(long)row*C_ + ch*4] =
        *(const ushort4*)&Os[row*132 + ch*4];
  }
}

extern "C" void kernel_launch(void* const* d_in, const int* in_sizes, int n_in,
                              void* d_out, int out_size, void* d_ws, size_t ws_size,
                              hipStream_t stream){
  const float* x_cls   = (const float*)d_in[0];
  const float* x_patch = (const float*)d_in[1];
  const float* norm_x_w = (const float*)d_in[2];
  const float* norm_x_b = (const float*)d_in[3];
  const float* pq_w  = (const float*)d_in[4];
  const float* pq_b  = (const float*)d_in[5];
  const float* ncls_w = (const float*)d_in[6];
  const float* ncls_b = (const float*)d_in[7];
  const float* pkv_w = (const float*)d_in[8];
  const float* pkv_b = (const float*)d_in[9];
  const float* fc1_w = (const float*)d_in[10];
  const float* fc1_b = (const float*)d_in[11];
  const float* bn1_g = (const float*)d_in[12];
  const float* bn1_b = (const float*)d_in[13];
  const float* mr_w  = (const float*)d_in[14];
  const float* mr_b  = (const float*)d_in[15];
  const float* bn2_g = (const float*)d_in[16];
  const float* bn2_b = (const float*)d_in[17];
  const float* fc2_w = (const float*)d_in[18];
  const float* fc2_b = (const float*)d_in[19];
  const float* bn3_g = (const float*)d_in[20];
  const float* bn3_b = (const float*)d_in[21];
  const float* proj_w = (const float*)d_in[22];
  const float* proj_b = (const float*)d_in[23];

  float* ws = (float*)d_ws;
  float* part   = ws + OFF_PART;
  float* ebb    = ws + OFF_EBB;
  float* kvbuf  = ws + OFF_KV;
  float* amapT  = ws + OFF_AMAPT;
  float* xf     = ws + OFF_XF;
  float* sqbuf  = ws + OFF_SQ;
  float* goutT  = ws + OFF_GOUTT;
  float* pbuf   = ws + OFF_PB;
  float2* candb = (float2*)(ws + OFF_CAND);
  unsigned short* Eb     = (unsigned short*)(ws + OFF_EB);
  unsigned short* xub    = (unsigned short*)(ws + OFF_XUB);
  unsigned short* w1bd   = (unsigned short*)(ws + OFF_W1BD);
  unsigned short* fc2b16 = (unsigned short*)(ws + OFF_FC2B);
  unsigned short* ybuf   = (unsigned short*)(ws + OFF_Y);
  unsigned short* fc1b16 = (unsigned short*)(ws + OFF_FC1B);
  unsigned short* xcb    = (unsigned short*)(ws + OFF_XCB);
  unsigned short* pkvb16 = (unsigned short*)(ws + OFF_PKVB);
  unsigned short* aob = (unsigned short*)(ws + OFF_AOB);
  unsigned short* wpb = (unsigned short*)(ws + OFF_WPB);
  float* out = (float*)d_out;

  k_pre<<<2128, 256, 0, stream>>>(x_patch, part, x_cls, ncls_w, ncls_b, xcb,
                                  pkv_w, pkvb16, proj_w, wpb,
                                  mr_w, fc2_w, fc1_w, w1bd, fc2b16, fc1b16);
  k_kv_mfma<<<128, 256, 0, stream>>>(xcb, pkvb16, pkv_b, kvbuf);
  k_eprep<<<dim3(16,5,8), 256, 0, stream>>>(kvbuf, pq_w, pq_b, part, norm_x_w, norm_x_b, Eb, ebb, pbuf);
  k_amap_fc1<<<dim3(16,16), 256, 0, stream>>>(Eb, x_patch, ebb, pbuf, fc1b16, fc1_b, bn1_g, bn1_b,
                                              amapT, xf, xub, sqbuf);
  k_negd_cand<<<dim3(8,8,16), 256, 0, stream>>>(xub, sqbuf, candb);
  k_merge_y<<<4096, 256, 0, stream>>>(candb, xf, ybuf);
  k_mixer_mfma<<<256, 256, 0, stream>>>(ybuf, w1bd, mr_b, bn2_g, bn2_b,
                                        fc2b16, fc2_b, bn3_g, bn3_b, amapT, goutT);
  k_softmax_pv<<<dim3(64,16), 256, 0, stream>>>(goutT, kvbuf, aob);
  k_gemm_mfma<true><<<dim3(8,4,16), 256, 0, stream>>>(wpb, aob, proj_b, x_patch, out);
}

// Round 14
// 161.263 us; speedup vs baseline: 1.6782x; 1.6782x over previous
//
#include <hip/hip_runtime.h>
#include <math.h>

#define DI __device__ __forceinline__

constexpr int B_ = 16, CLS_ = 20, C_ = 512, H_ = 4, HD_ = 128, N_ = 1024, G_ = 80, G2_ = 160, K_ = 9;
constexpr float EPS_ = 1e-5f;
constexpr float BNS_ = 0.9999950000374997f;     // 1/sqrt(1+1e-5)
constexpr float SCALE_ = 0.08838834764831845f;  // 128^-0.5
constexpr float INVSQRT2_ = 0.7071067811865475f;

typedef __attribute__((ext_vector_type(8))) short bf16x8;
typedef __attribute__((ext_vector_type(4))) float f32x4;

// ---- workspace layout (float slots) ----
constexpr long OFF_PART  = 0;                      // 2048
constexpr long OFF_EB    = 4096;                   // E bf16 [16][128][512] = 524288 slots
constexpr long OFF_EBB   = OFF_EB    + 524288;     // 1280 fp32
constexpr long OFF_KV    = OFF_EBB   + 2048;       // 16*20*1024 fp32
constexpr long OFF_AMAPT = OFF_KV    + 327680;     // 16*1024*80 fp32
constexpr long OFF_XF    = OFF_AMAPT + 1310720;
constexpr long OFF_XUB   = OFF_XF    + 1310720;    // bf16 16*1024*96 = 786432 slots
constexpr long OFF_W1BD  = OFF_XUB   + 786432;     // 16384
constexpr long OFF_FC2B  = OFF_W1BD  + 16384;      // 8192
constexpr long OFF_SQ    = OFF_FC2B  + 8192;       // 16384
constexpr long OFF_NEGD  = OFF_SQ    + 16384;      // 16*1024*1024 fp32; overlays aob (late)
constexpr long OFF_GOUTT = OFF_NEGD  + 16777216 + 147456;  // 1310720
constexpr long OFF_WPB   = OFF_GOUTT + 1310720;    // 131072 (proj_w bf16)
constexpr long OFF_Y     = OFF_WPB   + 131072;     // 1310720
constexpr long OFF_FC1B  = OFF_Y     + 1310720;    // fc1_w bf16 [80][96] -> 4096
constexpr long OFF_PB    = OFF_FC1B  + 4096;       // bias partials [16][8][80] -> 10240
constexpr long OFF_XCB   = OFF_PB    + 10240;      // cls-LN bf16 [16][32][512] -> 131072
constexpr long OFF_PKVB  = OFF_XCB   + 131072;     // pkv_w bf16 [1024][512] -> 262144

DI float wsum(float v){
#pragma unroll
  for(int d=1; d<64; d<<=1) v += __shfl_xor(v, d);
  return v;
}
DI unsigned short f2b(float f){
  unsigned u = __float_as_uint(f);
  unsigned r = (u + 0x7FFFu + ((u >> 16) & 1u)) >> 16;
  return (unsigned short)r;
}

#define GLOAD16(g, s) __builtin_amdgcn_global_load_lds((const __attribute__((address_space(1))) void*)(g), \
                        (__attribute__((address_space(3))) void*)(s), 16, 0, 0)

// K_pre: uniform short blocks, tiny LDS.
__global__ __launch_bounds__(256) void k_pre(const float* __restrict__ x, float* __restrict__ part,
                                             const float* __restrict__ xcls,
                                             const float* __restrict__ ncw, const float* __restrict__ ncb,
                                             unsigned short* __restrict__ xcb,
                                             const float* __restrict__ pkvw, unsigned short* __restrict__ pkvb16,
                                             const float* __restrict__ projw, unsigned short* __restrict__ wpb,
                                             const float* __restrict__ mrw, const float* __restrict__ fc2w,
                                             const float* __restrict__ fc1w,
                                             unsigned short* __restrict__ w1bd, unsigned short* __restrict__ fc2b16,
                                             unsigned short* __restrict__ fc1b16){
  __shared__ float rs[4], rss[4];
  int blk = blockIdx.x, t = threadIdx.x;
  if(blk < 1024){
    const float4* xp = (const float4*)x;
    long base4 = (long)blk * 2048;
    float s = 0.f, ss = 0.f;
#pragma unroll
    for(int j=0;j<8;++j){
      float4 v = xp[base4 + t + 256*j];
      s  += v.x + v.y + v.z + v.w;
      ss += v.x*v.x + v.y*v.y + v.z*v.z + v.w*v.w;
    }
    s = wsum(s); ss = wsum(ss);
    int wv = t >> 6;
    if((t & 63) == 0){ rs[wv] = s; rss[wv] = ss; }
    __syncthreads();
    if(t == 0){
      part[blk*2]   = rs[0]+rs[1]+rs[2]+rs[3];
      part[blk*2+1] = rss[0]+rss[1]+rss[2]+rss[3];
    }
    return;
  }
  if(blk < 1040){
    int b = blk - 1024;
    int wv = t >> 6, l = t & 63;
    for(int cls = wv; cls < 32; cls += 4){
      unsigned short* orow = xcb + ((long)b*32 + cls)*512;
      if(cls < CLS_){
        const float* xr = xcls + ((long)b*CLS_ + cls) * C_;
        float vals[8];
        float s = 0.f, ss = 0.f;
#pragma unroll
        for(int j=0;j<8;++j){ float v = xr[l + 64*j]; vals[j] = v; s += v; ss += v*v; }
        s = wsum(s); ss = wsum(ss);
        float m = s / (float)C_;
        float var = ss / (float)C_ - m*m;
        float inv = 1.0f / sqrtf(var + EPS_);
#pragma unroll
        for(int j=0;j<8;++j){
          int c = l + 64*j;
          orow[c] = f2b((vals[j]-m)*inv*ncw[c] + ncb[c]);
        }
      } else {
#pragma unroll
        for(int j=0;j<8;++j) orow[l + 64*j] = 0;
      }
    }
    return;
  }
  if(blk < 1296){
    long i = (long)(blk - 1040)*256 + t;
    float4 v = ((const float4*)projw)[i];
    uint2 o;
    o.x = (unsigned)f2b(v.x) | ((unsigned)f2b(v.y) << 16);
    o.y = (unsigned)f2b(v.z) | ((unsigned)f2b(v.w) << 16);
    ((uint2*)wpb)[i] = o;
    return;
  }
  if(blk < 1808){
    long i = (long)(blk - 1296)*256 + t;
    float4 v = ((const float4*)pkvw)[i];
    uint2 o;
    o.x = (unsigned)f2b(v.x) | ((unsigned)f2b(v.y) << 16);
    o.y = (unsigned)f2b(v.z) | ((unsigned)f2b(v.w) << 16);
    ((uint2*)pkvb16)[i] = o;
    return;
  }
  int row = blk - 1808;
  if(row < 160){
    if(t < 160){
      unsigned short v = 0;
      if(t/40 == row/40) v = f2b(mrw[row*40 + (t % 40)]);
      w1bd[row*160 + t] = v;
    }
  } else if(row < 240){
    if(t < 160) fc2b16[(row-160)*160 + t] = f2b(fc2w[(long)(row-160)*160 + t]);
  } else if(row < 320){
    int r = row - 240;
    if(t < 96) fc1b16[r*96 + t] = (t < G_) ? f2b(fc1w[(long)r*G_ + t]) : (unsigned short)0;
  }
}

// kv projection via MFMA
__global__ __launch_bounds__(256) void k_kv_mfma(const unsigned short* __restrict__ xcb,
                                                 const unsigned short* __restrict__ pkvb16,
                                                 const float* __restrict__ pkvb,
                                                 float* __restrict__ kv){
  __shared__ unsigned short Al[4096];
  __shared__ unsigned short Bl[1024];
  int b = blockIdx.x >> 3, o0 = (blockIdx.x & 7)*128;
  int t = threadIdx.x, w = t >> 6, l = t & 63;
  f32x4 acc[2][2] = {};
  const unsigned short* At = pkvb16 + (long)(o0 + w*16 + (l>>2))*512 + (l&3)*8;
  const unsigned short* Bt = xcb + ((long)b*32 + w*16 + (l>>2))*512 + (l&3)*8;
  int kq = (l >> 4)*8;
  for(int k0 = 0; k0 < 512; k0 += 32){
    if(k0) __syncthreads();
    GLOAD16(At + k0,          &Al[w*512]);
    GLOAD16(At + 64*512 + k0, &Al[2048 + w*512]);
    if(w < 2) GLOAD16(Bt + k0, &Bl[w*512]);
    __syncthreads();
    bf16x8 af[2], bfr[2];
#pragma unroll
    for(int mi=0; mi<2; ++mi) af[mi]  = *(const bf16x8*)&Al[(w*32 + mi*16 + (l & 15))*32 + kq];
#pragma unroll
    for(int ni=0; ni<2; ++ni) bfr[ni] = *(const bf16x8*)&Bl[(ni*16 + (l & 15))*32 + kq];
#pragma unroll
    for(int mi=0; mi<2; ++mi)
#pragma unroll
      for(int ni=0; ni<2; ++ni)
        acc[mi][ni] = __builtin_amdgcn_mfma_f32_16x16x32_bf16(af[mi], bfr[ni], acc[mi][ni], 0, 0, 0);
  }
  int r0 = (l >> 4)*4;
#pragma unroll
  for(int mi=0; mi<2; ++mi){
#pragma unroll
    for(int r=0; r<4; ++r){
      int o = o0 + w*32 + mi*16 + r0 + r;
      float bi = pkvb[o];
#pragma unroll
      for(int ni=0; ni<2; ++ni){
        int cls = ni*16 + (l & 15);
        if(cls < CLS_) kv[((long)b*CLS_ + cls)*1024 + o] = acc[mi][ni][r] + bi;
      }
    }
  }
}

// E prep: inline batch stats; folds patch-norm affine into E' and bias partials.
__global__ __launch_bounds__(256) void k_eprep(const float* __restrict__ kv, const float* __restrict__ pqw,
                                               const float* __restrict__ pqb, const float* __restrict__ partbuf,
                                               const float* __restrict__ nw, const float* __restrict__ nbv,
                                               unsigned short* __restrict__ Eb, float* __restrict__ ebb,
                                               float* __restrict__ pb){
  int b = blockIdx.x, hh = blockIdx.y, cch = blockIdx.z, t = threadIdx.x;
  if(hh == 4){
    if(cch == 0){
      unsigned* z = (unsigned*)(Eb + ((long)b*128 + 80)*512);
      for(int i=t; i<12288; i+=256) z[i] = 0;
    }
    return;
  }
  __shared__ float sst[2];
  __shared__ float key[CLS_][HD_];
  __shared__ float part[4][CLS_][64];
  if(t < 64){
    float s  = partbuf[(b*64+t)*2];
    float ss = partbuf[(b*64+t)*2+1];
    s = wsum(s); ss = wsum(ss);
    if(t == 0){
      const float cnt = (float)(C_ * N_);
      float m = s / cnt;
      sst[0] = m;
      sst[1] = 1.0f / sqrtf(ss / cnt - m*m + EPS_);
    }
  }
  int h = hh, c0 = cch*64;
  for(int i=t; i<CLS_*HD_; i+=256){
    int cls = i >> 7, d = i & 127;
    key[cls][d] = kv[((long)b*CLS_+cls)*1024 + h*HD_ + d];
  }
  __syncthreads();
  float m = sst[0], inv = sst[1];
  int c = t & 63, ds = t >> 6;
  float acc[CLS_] = {};
  const float* wp = pqw + ((long)(h*HD_ + ds*32))*C_ + c0 + c;
#pragma unroll 8
  for(int di=0; di<32; ++di){
    float wv = wp[(long)di*C_];
#pragma unroll
    for(int cls=0; cls<CLS_; ++cls) acc[cls] += key[cls][ds*32+di]*wv;
  }
#pragma unroll
  for(int cls=0; cls<CLS_; ++cls) part[ds][cls][c] = acc[cls];
  __syncthreads();
  for(int i=t; i<CLS_*64; i+=256){
    int cls = i >> 6, cc = i & 63;
    float v = (part[0][cls][cc]+part[1][cls][cc]+part[2][cls][cc]+part[3][cls][cc]) * SCALE_;
    int cg = c0 + cc;
    float a = inv * nw[cg];
    float bbv = nbv[cg] - m*a;
    Eb[((long)b*128 + h*CLS_ + cls)*512 + cg] = f2b(v*a);
    part[0][cls][cc] = v*bbv;
  }
  __syncthreads();
  if(t < CLS_){
    float s = 0.f;
    for(int cc=0; cc<64; ++cc) s += part[0][t][cc];
    pb[((long)b*8 + cch)*G_ + h*CLS_ + t] = s;
  }
  if(cch == 0 && t >= 64 && t < 64 + CLS_){
    int tt = t - 64;
    float bacc = 0.f;
    for(int d=0; d<HD_; ++d) bacc += key[tt][d]*pqb[h*HD_+d];
    ebb[b*G_ + h*CLS_ + tt] = bacc*SCALE_;
  }
}

// amap GEMM + fused fc1
__global__ __launch_bounds__(256) void k_amap_fc1(const unsigned short* __restrict__ Eb,
                                                  const float* __restrict__ xp,
                                                  const float* __restrict__ ebb,
                                                  const float* __restrict__ pb,
                                                  const unsigned short* __restrict__ w1b,
                                                  const float* __restrict__ f1bias,
                                                  const float* __restrict__ g1, const float* __restrict__ b1,
                                                  float* __restrict__ amapT,
                                                  float* __restrict__ xf, unsigned short* __restrict__ xub,
                                                  float* __restrict__ sq){
  __shared__ unsigned short Xl[64*520];
  __shared__ unsigned short Bgl[4096];
  unsigned short* A1 = Xl;
  int b = blockIdx.y, n0 = blockIdx.x*64;
  int t = threadIdx.x, w = t >> 6, l = t & 63;
  int wr = w >> 1, wc = w & 1;
  {
    int nb = t & 7, cl = t >> 3;
    const float* xb = xp + (long)b*C_*N_ + n0 + nb*8;
#pragma unroll 4
    for(int pass=0; pass<16; ++pass){
      int c = pass*32 + cl;
      const float* src = xb + (long)c*N_;
      float4 v0 = *(const float4*)src;
      float4 v1 = *(const float4*)(src+4);
      int base = (nb*8)*520 + c;
      Xl[base         ] = f2b(v0.x);
      Xl[base + 520   ] = f2b(v0.y);
      Xl[base + 520*2 ] = f2b(v0.z);
      Xl[base + 520*3 ] = f2b(v0.w);
      Xl[base + 520*4 ] = f2b(v1.x);
      Xl[base + 520*5 ] = f2b(v1.y);
      Xl[base + 520*6 ] = f2b(v1.z);
      Xl[base + 520*7 ] = f2b(v1.w);
    }
  }
  __syncthreads();
  f32x4 acc[2][4] = {};
  const unsigned short* Bt = Eb + ((long)b*128 + w*16 + (l>>2))*512 + (l&3)*8;
  int ra = wr*32 + (l & 15);
  int rb = wc*64 + (l & 15);
  int kq = (l >> 4) * 8;
  for(int k0 = 0; k0 < 512; k0 += 32){
    if(k0) __syncthreads();
    GLOAD16(Bt + k0,          &Bgl[w*512]);
    GLOAD16(Bt + 64*512 + k0, &Bgl[2048 + w*512]);
    __syncthreads();
    bf16x8 af[2], bfr[4];
#pragma unroll
    for(int rt=0; rt<2; ++rt) af[rt]  = *(const bf16x8*)&Xl[(ra + rt*16)*520 + k0 + kq];
#pragma unroll
    for(int ct=0; ct<4; ++ct) bfr[ct] = *(const bf16x8*)&Bgl[(rb + ct*16)*32 + kq];
#pragma unroll
    for(int rt=0; rt<2; ++rt)
#pragma unroll
      for(int ct=0; ct<4; ++ct)
        acc[rt][ct] = __builtin_amdgcn_mfma_f32_16x16x32_bf16(af[rt], bfr[ct], acc[rt][ct], 0, 0, 0);
  }
  float bias4[4];
#pragma unroll
  for(int ct=0; ct<4; ++ct){
    int g = wc*64 + ct*16 + (l & 15);
    float bi = 0.f;
    if(g < G_){
      bi = ebb[b*G_ + g];
#pragma unroll
      for(int cc=0; cc<8; ++cc) bi += pb[((long)b*8 + cc)*G_ + g];
    }
    bias4[ct] = bi;
  }
  __syncthreads();
  int r0 = (l >> 4)*4;
#pragma unroll
  for(int rt=0; rt<2; ++rt){
#pragma unroll
    for(int r=0; r<4; ++r){
      int lrow = wr*32 + rt*16 + r0 + r;
      long rowb = ((long)b*N_ + n0 + lrow)*G_;
#pragma unroll
      for(int ct=0; ct<4; ++ct){
        int g = wc*64 + ct*16 + (l & 15);
        if(g < G_){
          float val = acc[rt][ct][r] + bias4[ct];
          amapT[rowb + g] = val;
          A1[lrow*96 + g] = f2b(val);
        } else if(g < 96){
          A1[lrow*96 + g] = 0;
        }
      }
    }
  }
  __syncthreads();
  int lr = l & 15, lk = l >> 4;
  bf16x8 ay[3];
  const unsigned short* arow = &A1[(w*16 + lr)*96 + lk*8];
#pragma unroll
  for(int ks=0; ks<3; ++ks) ay[ks] = *(const bf16x8*)&arow[ks*32];
  f32x4 acc5[5] = {};
  const unsigned short* wrow = w1b + (long)lr*96 + lk*8;
#pragma unroll
  for(int ks=0; ks<3; ++ks){
#pragma unroll
    for(int ct=0; ct<5; ++ct){
      bf16x8 bw = *(const bf16x8*)&wrow[ct*16*96 + ks*32];
      acc5[ct] = __builtin_amdgcn_mfma_f32_16x16x32_bf16(ay[ks], bw, acc5[ct], 0, 0, 0);
    }
  }
  float v[5][4];
  float ssq[4] = {0.f,0.f,0.f,0.f};
#pragma unroll
  for(int ct=0; ct<5; ++ct){
    int o = ct*16 + lr;
    float bi = f1bias[o], ga = g1[o]*BNS_, bb = b1[o];
#pragma unroll
    for(int i=0;i<4;++i){
      float vv = (acc5[ct][i] + bi)*ga + bb;
      v[ct][i] = vv;
      ssq[i] += vv*vv;
    }
  }
#pragma unroll
  for(int d=1; d<16; d<<=1){
#pragma unroll
    for(int i=0;i<4;++i) ssq[i] += __shfl_xor(ssq[i], d);
  }
  long row0g = (long)b*N_ + n0 + w*16;
#pragma unroll
  for(int i=0;i<4;++i){
    long row = row0g + lk*4 + i;
    float invn = 1.0f / fmaxf(sqrtf(ssq[i]), 1e-12f);
#pragma unroll
    for(int ct=0; ct<5; ++ct){
      int o = ct*16 + lr;
      xf[row*G_ + o] = v[ct][i];
      xub[row*96 + o] = f2b(v[ct][i]*invn);
    }
    xub[row*96 + 80 + lr] = 0;
    if(lr == 0) sq[row] = ssq[i]*invn*invn;
  }
}

// MFMA GEMM: Out[b][o][n] = sum_c Wb[o][c]*Xb[b][n][c] + bias[o] (+Res)
template<bool RES>
__global__ __launch_bounds__(256) void k_gemm_mfma(const unsigned short* __restrict__ Wb,
                                                   const unsigned short* __restrict__ Xb,
                                                   const float* __restrict__ bias,
                                                   const float* __restrict__ Res,
                                                   float* __restrict__ Out){
  __shared__ unsigned short Al[4096];
  __shared__ unsigned short Bl[4096];
  int b = blockIdx.z;
  int o0 = blockIdx.y*128, n0 = blockIdx.x*128;
  int t = threadIdx.x, w = t >> 6, l = t & 63;
  int wr = w >> 1, wc = w & 1;
  f32x4 acc[4][4] = {};
  const unsigned short* Wt = Wb + (long)(o0 + w*16 + (l>>2))*512 + (l&3)*8;
  const unsigned short* Xt = Xb + ((long)b*N_ + n0 + w*16 + (l>>2))*512 + (l&3)*8;
  int ra = wr*64 + (l & 15);
  int rb = wc*64 + (l & 15);
  int kq = (l >> 4) * 8;
  for(int k0 = 0; k0 < 512; k0 += 32){
    if(k0) __syncthreads();
    GLOAD16(Wt + k0,            &Al[w*512]);
    GLOAD16(Wt + 64*512 + k0,   &Al[2048 + w*512]);
    GLOAD16(Xt + k0,            &Bl[w*512]);
    GLOAD16(Xt + 64*512 + k0,   &Bl[2048 + w*512]);
    __syncthreads();
    bf16x8 af[4], bfr[4];
#pragma unroll
    for(int i=0;i<4;++i){
      af[i]  = *(const bf16x8*)&Al[(ra + i*16)*32 + kq];
      bfr[i] = *(const bf16x8*)&Bl[(rb + i*16)*32 + kq];
    }
#pragma unroll
    for(int mi=0; mi<4; ++mi)
#pragma unroll
      for(int ni=0; ni<4; ++ni)
        acc[mi][ni] = __builtin_amdgcn_mfma_f32_16x16x32_bf16(af[mi], bfr[ni], acc[mi][ni], 0, 0, 0);
  }
  long obase = ((long)b*C_ + o0 + wr*64)*N_ + n0 + wc*64 + (l & 15);
  int r0 = (l >> 4) * 4;
#pragma unroll
  for(int mi=0; mi<4; ++mi){
#pragma unroll
    for(int r=0; r<4; ++r){
      int row = mi*16 + r0 + r;
      float bi = bias[o0 + wr*64 + row];
#pragma unroll
      for(int ni=0; ni<4; ++ni){
        long oi = obase + (long)row*N_ + ni*16;
        float v = acc[mi][ni][r] + bi;
        if(RES) v += Res[oi];
        Out[oi] = v;
      }
    }
  }
}

// neg_d via bf16 MFMA
__global__ __launch_bounds__(256) void k_negd_mfma(const unsigned short* __restrict__ xub,
                                                   const float* __restrict__ sq,
                                                   float* __restrict__ negd){
  __shared__ unsigned short Al[128*96];
  __shared__ unsigned short Bl[128*96];
  int b = blockIdx.z;
  int n0 = blockIdx.y*128, m0 = blockIdx.x*128;
  int t = threadIdx.x, w = t >> 6, l = t & 63;
  int wr = w >> 1, wc = w & 1;
  const unsigned short* gA = xub + ((long)b*N_ + n0)*96;
  const unsigned short* gB = xub + ((long)b*N_ + m0)*96;
#pragma unroll
  for(int rd=0; rd<6; ++rd){
    int chunk = rd*4 + w;
    GLOAD16(gA + chunk*512 + l*8, &Al[chunk*512]);
    GLOAD16(gB + chunk*512 + l*8, &Bl[chunk*512]);
  }
  __syncthreads();
  f32x4 acc[4][4] = {};
  int ra = wr*64 + (l & 15);
  int rb = wc*64 + (l & 15);
#pragma unroll
  for(int ks=0; ks<3; ++ks){
    int kq = ks*32 + (l >> 4)*8;
    bf16x8 af[4], bfr[4];
#pragma unroll
    for(int i=0;i<4;++i){
      af[i]  = *(const bf16x8*)&Al[(ra + i*16)*96 + kq];
      bfr[i] = *(const bf16x8*)&Bl[(rb + i*16)*96 + kq];
    }
#pragma unroll
    for(int mi=0; mi<4; ++mi)
#pragma unroll
      for(int ni=0; ni<4; ++ni)
        acc[mi][ni] = __builtin_amdgcn_mfma_f32_16x16x32_bf16(af[mi], bfr[ni], acc[mi][ni], 0, 0, 0);
  }
  int r0 = (l >> 4)*4;
  const float* sqb = sq + (long)b*N_;
#pragma unroll
  for(int mi=0; mi<4; ++mi){
#pragma unroll
    for(int r=0; r<4; ++r){
      int n = n0 + wr*64 + mi*16 + r0 + r;
      float sn = sqb[n];
      long row = ((long)b*N_ + n)*N_;
#pragma unroll
      for(int ni=0; ni<4; ++ni){
        int m = m0 + wc*64 + ni*16 + (l & 15);
        negd[row + m] = 2.f*acc[mi][ni][r] - sn - sqb[m];
      }
    }
  }
}

// top-9 per row then gather neighbor-max -> y bf16. one wave per row. float4 negd reads.
__global__ __launch_bounds__(256) void k_topk_y(const float* __restrict__ negd, const float* __restrict__ xf,
                                                unsigned short* __restrict__ y){
  int t = threadIdx.x, wv = t >> 6, l = t & 63;
  long r = (long)blockIdx.x*4 + wv;
  long b = r >> 10;
  const float4* row4 = (const float4*)(negd + r*N_);
  float vals[16];
#pragma unroll
  for(int cq=0; cq<4; ++cq){
    float4 v = row4[cq*64 + l];
    vals[cq*4]   = v.x;
    vals[cq*4+1] = v.y;
    vals[cq*4+2] = v.z;
    vals[cq*4+3] = v.w;
  }
  // index of vals[j] = (j>>2)*256 + 4*l + (j&3)  — monotonic in j per lane
  int nbs[K_];
#pragma unroll
  for(int p=0; p<K_; ++p){
    float bv = vals[0]; int bj = 0;
#pragma unroll
    for(int j=1;j<16;++j) if(vals[j] > bv){ bv = vals[j]; bj = j; }
    int bm = (bj >> 2)*256 + 4*l + (bj & 3);
#pragma unroll
    for(int d=1; d<64; d<<=1){
      float ov = __shfl_xor(bv, d);
      int   om = __shfl_xor(bm, d);
      if(ov > bv || (ov == bv && om < bm)){ bv = ov; bm = om; }
    }
    nbs[p] = bm;
#pragma unroll
    for(int j=0;j<16;++j) if(bm == (j >> 2)*256 + 4*l + (j & 3)) vals[j] = -INFINITY;
  }
  const float* frow = xf + r*G_;
  int o2s = (l < 16) ? (64 + l) : 0;
  float f0 = frow[l];
  float f1 = frow[o2s];
  float m0 = -INFINITY, m1 = -INFINITY;
#pragma unroll
  for(int k=0;k<K_;++k){
    const float* nr = xf + ((long)b*N_ + nbs[k])*G_;
    m0 = fmaxf(m0, nr[l]);
    m1 = fmaxf(m1, nr[o2s]);
  }
  unsigned short* yr = y + r*G2_;
  ushort2 u0; u0.x = f2b(f0); u0.y = f2b(m0 - f0);
  *(ushort2*)&yr[2*l] = u0;
  if(l < 16){
    ushort2 u1; u1.x = f2b(f1); u1.y = f2b(m1 - f1);
    *(ushort2*)&yr[128 + 2*l] = u1;
  }
}

// MFMA mixer + bn2 + gelu + fc2 + bn3 + amap -> goutT
__global__ __launch_bounds__(256) void k_mixer_mfma(const unsigned short* __restrict__ y,
                                                    const unsigned short* __restrict__ w1bd,
                                                    const float* __restrict__ mrb,
                                                    const float* __restrict__ g2, const float* __restrict__ b2,
                                                    const unsigned short* __restrict__ fc2b16,
                                                    const float* __restrict__ fc2bias,
                                                    const float* __restrict__ g3, const float* __restrict__ b3,
                                                    const float* __restrict__ amapT, float* __restrict__ goutT){
  __shared__ unsigned short zl[4][16][G2_];
  int t = threadIdx.x, w = t >> 6, l = t & 63;
  long row0 = ((long)blockIdx.x*4 + w)*16;
  int lr = l & 15, lk = l >> 4;
  bf16x8 ay[5];
  const unsigned short* yrow = y + (row0 + lr)*G2_ + lk*8;
#pragma unroll
  for(int ks=0; ks<5; ++ks) ay[ks] = *(const bf16x8*)&yrow[ks*32];
  f32x4 accz[10] = {};
  const unsigned short* wb = w1bd + (long)lr*G2_ + lk*8;
#pragma unroll
  for(int ks=0; ks<5; ++ks){
#pragma unroll
    for(int ct=0; ct<10; ++ct){
      bf16x8 bw = *(const bf16x8*)&wb[ct*16*G2_ + ks*32];
      accz[ct] = __builtin_amdgcn_mfma_f32_16x16x32_bf16(ay[ks], bw, accz[ct], 0, 0, 0);
    }
  }
#pragma unroll
  for(int ct=0; ct<10; ++ct){
    int o = ct*16 + lr;
    float bi = mrb[o], ga = g2[o]*BNS_, bb = b2[o];
#pragma unroll
    for(int i=0;i<4;++i){
      float v = (accz[ct][i] + bi)*ga + bb;
      float zz = v * 0.5f * (1.0f + erff(v * INVSQRT2_));
      zl[w][lk*4 + i][o] = f2b(zz);
    }
  }
  __syncthreads();
  bf16x8 az[5];
#pragma unroll
  for(int ks=0; ks<5; ++ks) az[ks] = *(const bf16x8*)&zl[w][lr][ks*32 + lk*8];
  f32x4 acc2[5] = {};
  const unsigned short* fb = fc2b16 + (long)lr*G2_ + lk*8;
#pragma unroll
  for(int ks=0; ks<5; ++ks){
#pragma unroll
    for(int ct=0; ct<5; ++ct){
      bf16x8 bw = *(const bf16x8*)&fb[ct*16*G2_ + ks*32];
      acc2[ct] = __builtin_amdgcn_mfma_f32_16x16x32_bf16(az[ks], bw, acc2[ct], 0, 0, 0);
    }
  }
#pragma unroll
  for(int ct=0; ct<5; ++ct){
    int o = ct*16 + lr;
    float bi = fc2bias[o], ga = g3[o]*BNS_, bb = b3[o];
#pragma unroll
    for(int i=0;i<4;++i){
      long row = row0 + lk*4 + i;
      float v = (acc2[ct][i] + bi)*ga + bb + amapT[row*G_ + o];
      goutT[row*G_ + o] = v;
    }
  }
}

// per-thread softmax + MFMA PV -> bf16 aob[b][n][c]
__global__ __launch_bounds__(256) void k_softmax_pv(const float* __restrict__ goutT, const float* __restrict__ kv,
                                                    unsigned short* __restrict__ aob){
  int bh = blockIdx.x; int b = bh >> 2, h = bh & 3;
  int n0 = blockIdx.y * 64;
  __shared__ unsigned short Vt[128*32];
  __shared__ unsigned short Pl[64*40];
  __shared__ unsigned short Os[64*132];
  int t = threadIdx.x, w = t >> 6, l = t & 63;
  if(t < 128){
    int d = t;
    const float* vb = kv + ((long)b*CLS_)*1024 + C_ + h*HD_ + d;
#pragma unroll
    for(int cls=0; cls<CLS_; ++cls) Vt[d*32+cls] = f2b(vb[(long)cls*1024]);
#pragma unroll
    for(int cls=CLS_; cls<32; ++cls) Vt[d*32+cls] = 0;
  }
  if(t < 64){
    int n = n0 + t;
    const float* gr = goutT + ((long)b*N_ + n)*G_ + h*CLS_;
    float x[CLS_];
    float mx = -INFINITY;
#pragma unroll
    for(int cls=0; cls<CLS_; ++cls){ x[cls] = gr[cls]; mx = fmaxf(mx, x[cls]); }
    float s = 0.f;
#pragma unroll
    for(int cls=0; cls<CLS_; ++cls){ x[cls] = expf(x[cls]-mx); s += x[cls]; }
    float inv = 1.0f / s;
#pragma unroll
    for(int cls=0; cls<CLS_; ++cls) Pl[t*40+cls] = f2b(x[cls]*inv);
#pragma unroll
    for(int cls=CLS_; cls<32; ++cls) Pl[t*40+cls] = 0;
  }
  __syncthreads();
  int lr = l & 15, kq = (l >> 4)*8;
  f32x4 acc[4][2] = {};
  bf16x8 af[4], bf2[2];
#pragma unroll
  for(int rt=0; rt<4; ++rt) af[rt] = *(const bf16x8*)&Pl[(rt*16+lr)*40 + kq];
#pragma unroll
  for(int ci=0; ci<2; ++ci) bf2[ci] = *(const bf16x8*)&Vt[((2*w+ci)*16+lr)*32 + kq];
#pragma unroll
  for(int rt=0; rt<4; ++rt)
#pragma unroll
    for(int ci=0; ci<2; ++ci)
      acc[rt][ci] = __builtin_amdgcn_mfma_f32_16x16x32_bf16(af[rt], bf2[ci], acc[rt][ci], 0, 0, 0);
  int r0 = (l >> 4)*4;
#pragma unroll
  for(int rt=0; rt<4; ++rt)
#pragma unroll
    for(int ci=0; ci<2; ++ci)
#pragma unroll
      for(int i=0; i<4; ++i)
        Os[(rt*16 + r0 + i)*132 + (2*w+ci)*16 + lr] = f2b(acc[rt][ci][i]);
  __syncthreads();
  unsigned short* ob = aob + ((long)b*N_ + n0)*C_ + h*HD_;
#pragma unroll
  for(int j=0; j<8; ++j){
    int idx = t + 256*j;
    int row = idx >> 5, ch = idx & 31;
    *(ushort4*)&ob[(long)row*C_ + ch*4] =
        *(const ushort4*)&Os[row*132 + ch*4];
  }
}

extern "C" void kernel_launch(void* const* d_in, const int* in_sizes, int n_in,
                              void* d_out, int out_size, void* d_ws, size_t ws_size,
                              hipStream_t stream){
  const float* x_cls   = (const float*)d_in[0];
  const float* x_patch = (const float*)d_in[1];
  const float* norm_x_w = (const float*)d_in[2];
  const float* norm_x_b = (const float*)d_in[3];
  const float* pq_w  = (const float*)d_in[4];
  const float* pq_b  = (const float*)d_in[5];
  const float* ncls_w = (const float*)d_in[6];
  const float* ncls_b = (const float*)d_in[7];
  const float* pkv_w = (const float*)d_in[8];
  const float* pkv_b = (const float*)d_in[9];
  const float* fc1_w = (const float*)d_in[10];
  const float* fc1_b = (const float*)d_in[11];
  const float* bn1_g = (const float*)d_in[12];
  const float* bn1_b = (const float*)d_in[13];
  const float* mr_w  = (const float*)d_in[14];
  const float* mr_b  = (const float*)d_in[15];
  const float* bn2_g = (const float*)d_in[16];
  const float* bn2_b = (const float*)d_in[17];
  const float* fc2_w = (const float*)d_in[18];
  const float* fc2_b = (const float*)d_in[19];
  const float* bn3_g = (const float*)d_in[20];
  const float* bn3_b = (const float*)d_in[21];
  const float* proj_w = (const float*)d_in[22];
  const float* proj_b = (const float*)d_in[23];

  float* ws = (float*)d_ws;
  float* part   = ws + OFF_PART;
  float* ebb    = ws + OFF_EBB;
  float* kvbuf  = ws + OFF_KV;
  float* amapT  = ws + OFF_AMAPT;
  float* xf     = ws + OFF_XF;
  float* sqbuf  = ws + OFF_SQ;
  float* negd   = ws + OFF_NEGD;
  float* goutT  = ws + OFF_GOUTT;
  float* pbuf   = ws + OFF_PB;
  unsigned short* Eb     = (unsigned short*)(ws + OFF_EB);
  unsigned short* xub    = (unsigned short*)(ws + OFF_XUB);
  unsigned short* w1bd   = (unsigned short*)(ws + OFF_W1BD);
  unsigned short* fc2b16 = (unsigned short*)(ws + OFF_FC2B);
  unsigned short* ybuf   = (unsigned short*)(ws + OFF_Y);
  unsigned short* fc1b16 = (unsigned short*)(ws + OFF_FC1B);
  unsigned short* xcb    = (unsigned short*)(ws + OFF_XCB);
  unsigned short* pkvb16 = (unsigned short*)(ws + OFF_PKVB);
  unsigned short* aob = (unsigned short*)(ws + OFF_NEGD);   // overlay: negd dead after topk_y
  unsigned short* wpb = (unsigned short*)(ws + OFF_WPB);
  float* out = (float*)d_out;

  k_pre<<<2128, 256, 0, stream>>>(x_patch, part, x_cls, ncls_w, ncls_b, xcb,
                                  pkv_w, pkvb16, proj_w, wpb,
                                  mr_w, fc2_w, fc1_w, w1bd, fc2b16, fc1b16);
  k_kv_mfma<<<128, 256, 0, stream>>>(xcb, pkvb16, pkv_b, kvbuf);
  k_eprep<<<dim3(16,5,8), 256, 0, stream>>>(kvbuf, pq_w, pq_b, part, norm_x_w, norm_x_b, Eb, ebb, pbuf);
  k_amap_fc1<<<dim3(16,16), 256, 0, stream>>>(Eb, x_patch, ebb, pbuf, fc1b16, fc1_b, bn1_g, bn1_b,
                                              amapT, xf, xub, sqbuf);
  k_negd_mfma<<<dim3(8,8,16), 256, 0, stream>>>(xub, sqbuf, negd);
  k_topk_y<<<4096, 256, 0, stream>>>(negd, xf, ybuf);
  k_mixer_mfma<<<256, 256, 0, stream>>>(ybuf, w1bd, mr_b, bn2_g, bn2_b,
                                        fc2b16, fc2_b, bn3_g, bn3_b, amapT, goutT);
  k_softmax_pv<<<dim3(64,16), 256, 0, stream>>>(goutT, kvbuf, aob);
  k_gemm_mfma<true><<<dim3(8,4,16), 256, 0, stream>>>(wpb, aob, proj_b, x_patch, out);
}

// Round 15
// 159.727 us; speedup vs baseline: 1.6943x; 1.0096x over previous
//
#include <hip/hip_runtime.h>
#include <math.h>

#define DI __device__ __forceinline__

constexpr int B_ = 16, CLS_ = 20, C_ = 512, H_ = 4, HD_ = 128, N_ = 1024, G_ = 80, G2_ = 160, K_ = 9;
constexpr float EPS_ = 1e-5f;
constexpr float BNS_ = 0.9999950000374997f;     // 1/sqrt(1+1e-5)
constexpr float SCALE_ = 0.08838834764831845f;  // 128^-0.5
constexpr float INVSQRT2_ = 0.7071067811865475f;

typedef __attribute__((ext_vector_type(8))) short bf16x8;
typedef __attribute__((ext_vector_type(4))) float f32x4;

// ---- workspace layout (float slots) ----
constexpr long OFF_PART  = 0;                      // 2048
constexpr long OFF_EB    = 4096;                   // E bf16 [16][128][512] = 524288 slots
constexpr long OFF_EBB   = OFF_EB    + 524288;     // 1280 fp32
constexpr long OFF_KV    = OFF_EBB   + 2048;       // 16*20*1024 fp32
constexpr long OFF_AMAPT = OFF_KV    + 327680;     // 16*1024*80 fp32
constexpr long OFF_XF    = OFF_AMAPT + 1310720;
constexpr long OFF_XUB   = OFF_XF    + 1310720;    // bf16 16*1024*96 = 786432 slots
constexpr long OFF_W1BD  = OFF_XUB   + 786432;     // 16384
constexpr long OFF_FC2B  = OFF_W1BD  + 16384;      // 8192
constexpr long OFF_SQ    = OFF_FC2B  + 8192;       // 16384
constexpr long OFF_NEGD  = OFF_SQ    + 16384;      // 16*1024*1024 fp32; overlays aob (late)
constexpr long OFF_GOUTT = OFF_NEGD  + 16777216 + 147456;  // 1310720
constexpr long OFF_WPB   = OFF_GOUTT + 1310720;    // 131072 (proj_w bf16)
constexpr long OFF_Y     = OFF_WPB   + 131072;     // 1310720
constexpr long OFF_FC1B  = OFF_Y     + 1310720;    // fc1_w bf16 [80][96] -> 4096
constexpr long OFF_PB    = OFF_FC1B  + 4096;       // bias partials [16][8][80] -> 10240
constexpr long OFF_XCB   = OFF_PB    + 10240;      // cls-LN bf16 [16][32][512] -> 131072
constexpr long OFF_PKVB  = OFF_XCB   + 131072;     // pkv_w bf16 [1024][512] -> 262144

DI float wsum(float v){
#pragma unroll
  for(int d=1; d<64; d<<=1) v += __shfl_xor(v, d);
  return v;
}
DI unsigned short f2b(float f){
  unsigned u = __float_as_uint(f);
  unsigned r = (u + 0x7FFFu + ((u >> 16) & 1u)) >> 16;
  return (unsigned short)r;
}

#define GLOAD16(g, s) __builtin_amdgcn_global_load_lds((const __attribute__((address_space(1))) void*)(g), \
                        (__attribute__((address_space(3))) void*)(s), 16, 0, 0)

// K_pre: uniform short blocks, tiny LDS.
__global__ __launch_bounds__(256) void k_pre(const float* __restrict__ x, float* __restrict__ part,
                                             const float* __restrict__ xcls,
                                             const float* __restrict__ ncw, const float* __restrict__ ncb,
                                             unsigned short* __restrict__ xcb,
                                             const float* __restrict__ pkvw, unsigned short* __restrict__ pkvb16,
                                             const float* __restrict__ projw, unsigned short* __restrict__ wpb,
                                             const float* __restrict__ mrw, const float* __restrict__ fc2w,
                                             const float* __restrict__ fc1w,
                                             unsigned short* __restrict__ w1bd, unsigned short* __restrict__ fc2b16,
                                             unsigned short* __restrict__ fc1b16){
  __shared__ float rs[4], rss[4];
  int blk = blockIdx.x, t = threadIdx.x;
  if(blk < 1024){
    const float4* xp = (const float4*)x;
    long base4 = (long)blk * 2048;
    float s = 0.f, ss = 0.f;
#pragma unroll
    for(int j=0;j<8;++j){
      float4 v = xp[base4 + t + 256*j];
      s  += v.x + v.y + v.z + v.w;
      ss += v.x*v.x + v.y*v.y + v.z*v.z + v.w*v.w;
    }
    s = wsum(s); ss = wsum(ss);
    int wv = t >> 6;
    if((t & 63) == 0){ rs[wv] = s; rss[wv] = ss; }
    __syncthreads();
    if(t == 0){
      part[blk*2]   = rs[0]+rs[1]+rs[2]+rs[3];
      part[blk*2+1] = rss[0]+rss[1]+rss[2]+rss[3];
    }
    return;
  }
  if(blk < 1040){
    int b = blk - 1024;
    int wv = t >> 6, l = t & 63;
    for(int cls = wv; cls < 32; cls += 4){
      unsigned short* orow = xcb + ((long)b*32 + cls)*512;
      if(cls < CLS_){
        const float* xr = xcls + ((long)b*CLS_ + cls) * C_;
        float vals[8];
        float s = 0.f, ss = 0.f;
#pragma unroll
        for(int j=0;j<8;++j){ float v = xr[l + 64*j]; vals[j] = v; s += v; ss += v*v; }
        s = wsum(s); ss = wsum(ss);
        float m = s / (float)C_;
        float var = ss / (float)C_ - m*m;
        float inv = 1.0f / sqrtf(var + EPS_);
#pragma unroll
        for(int j=0;j<8;++j){
          int c = l + 64*j;
          orow[c] = f2b((vals[j]-m)*inv*ncw[c] + ncb[c]);
        }
      } else {
#pragma unroll
        for(int j=0;j<8;++j) orow[l + 64*j] = 0;
      }
    }
    return;
  }
  if(blk < 1296){
    long i = (long)(blk - 1040)*256 + t;
    float4 v = ((const float4*)projw)[i];
    uint2 o;
    o.x = (unsigned)f2b(v.x) | ((unsigned)f2b(v.y) << 16);
    o.y = (unsigned)f2b(v.z) | ((unsigned)f2b(v.w) << 16);
    ((uint2*)wpb)[i] = o;
    return;
  }
  if(blk < 1808){
    long i = (long)(blk - 1296)*256 + t;
    float4 v = ((const float4*)pkvw)[i];
    uint2 o;
    o.x = (unsigned)f2b(v.x) | ((unsigned)f2b(v.y) << 16);
    o.y = (unsigned)f2b(v.z) | ((unsigned)f2b(v.w) << 16);
    ((uint2*)pkvb16)[i] = o;
    return;
  }
  int row = blk - 1808;
  if(row < 160){
    if(t < 160){
      unsigned short v = 0;
      if(t/40 == row/40) v = f2b(mrw[row*40 + (t % 40)]);
      w1bd[row*160 + t] = v;
    }
  } else if(row < 240){
    if(t < 160) fc2b16[(row-160)*160 + t] = f2b(fc2w[(long)(row-160)*160 + t]);
  } else if(row < 320){
    int r = row - 240;
    if(t < 96) fc1b16[r*96 + t] = (t < G_) ? f2b(fc1w[(long)r*G_ + t]) : (unsigned short)0;
  }
}

// kv projection via MFMA
__global__ __launch_bounds__(256) void k_kv_mfma(const unsigned short* __restrict__ xcb,
                                                 const unsigned short* __restrict__ pkvb16,
                                                 const float* __restrict__ pkvb,
                                                 float* __restrict__ kv){
  __shared__ unsigned short Al[4096];
  __shared__ unsigned short Bl[1024];
  int b = blockIdx.x >> 3, o0 = (blockIdx.x & 7)*128;
  int t = threadIdx.x, w = t >> 6, l = t & 63;
  f32x4 acc[2][2] = {};
  const unsigned short* At = pkvb16 + (long)(o0 + w*16 + (l>>2))*512 + (l&3)*8;
  const unsigned short* Bt = xcb + ((long)b*32 + w*16 + (l>>2))*512 + (l&3)*8;
  int kq = (l >> 4)*8;
  for(int k0 = 0; k0 < 512; k0 += 32){
    if(k0) __syncthreads();
    GLOAD16(At + k0,          &Al[w*512]);
    GLOAD16(At + 64*512 + k0, &Al[2048 + w*512]);
    if(w < 2) GLOAD16(Bt + k0, &Bl[w*512]);
    __syncthreads();
    bf16x8 af[2], bfr[2];
#pragma unroll
    for(int mi=0; mi<2; ++mi) af[mi]  = *(const bf16x8*)&Al[(w*32 + mi*16 + (l & 15))*32 + kq];
#pragma unroll
    for(int ni=0; ni<2; ++ni) bfr[ni] = *(const bf16x8*)&Bl[(ni*16 + (l & 15))*32 + kq];
#pragma unroll
    for(int mi=0; mi<2; ++mi)
#pragma unroll
      for(int ni=0; ni<2; ++ni)
        acc[mi][ni] = __builtin_amdgcn_mfma_f32_16x16x32_bf16(af[mi], bfr[ni], acc[mi][ni], 0, 0, 0);
  }
  int r0 = (l >> 4)*4;
#pragma unroll
  for(int mi=0; mi<2; ++mi){
#pragma unroll
    for(int r=0; r<4; ++r){
      int o = o0 + w*32 + mi*16 + r0 + r;
      float bi = pkvb[o];
#pragma unroll
      for(int ni=0; ni<2; ++ni){
        int cls = ni*16 + (l & 15);
        if(cls < CLS_) kv[((long)b*CLS_ + cls)*1024 + o] = acc[mi][ni][r] + bi;
      }
    }
  }
}

// E prep: inline batch stats; folds patch-norm affine into E' and bias partials.
__global__ __launch_bounds__(256) void k_eprep(const float* __restrict__ kv, const float* __restrict__ pqw,
                                               const float* __restrict__ pqb, const float* __restrict__ partbuf,
                                               const float* __restrict__ nw, const float* __restrict__ nbv,
                                               unsigned short* __restrict__ Eb, float* __restrict__ ebb,
                                               float* __restrict__ pb){
  int b = blockIdx.x, hh = blockIdx.y, cch = blockIdx.z, t = threadIdx.x;
  if(hh == 4){
    if(cch == 0){
      unsigned* z = (unsigned*)(Eb + ((long)b*128 + 80)*512);
      for(int i=t; i<12288; i+=256) z[i] = 0;
    }
    return;
  }
  __shared__ float sst[2];
  __shared__ float key[CLS_][HD_];
  __shared__ float part[4][CLS_][64];
  if(t < 64){
    float s  = partbuf[(b*64+t)*2];
    float ss = partbuf[(b*64+t)*2+1];
    s = wsum(s); ss = wsum(ss);
    if(t == 0){
      const float cnt = (float)(C_ * N_);
      float m = s / cnt;
      sst[0] = m;
      sst[1] = 1.0f / sqrtf(ss / cnt - m*m + EPS_);
    }
  }
  int h = hh, c0 = cch*64;
  for(int i=t; i<CLS_*HD_; i+=256){
    int cls = i >> 7, d = i & 127;
    key[cls][d] = kv[((long)b*CLS_+cls)*1024 + h*HD_ + d];
  }
  __syncthreads();
  float m = sst[0], inv = sst[1];
  int c = t & 63, ds = t >> 6;
  float acc[CLS_] = {};
  const float* wp = pqw + ((long)(h*HD_ + ds*32))*C_ + c0 + c;
#pragma unroll 8
  for(int di=0; di<32; ++di){
    float wv = wp[(long)di*C_];
#pragma unroll
    for(int cls=0; cls<CLS_; ++cls) acc[cls] += key[cls][ds*32+di]*wv;
  }
#pragma unroll
  for(int cls=0; cls<CLS_; ++cls) part[ds][cls][c] = acc[cls];
  __syncthreads();
  for(int i=t; i<CLS_*64; i+=256){
    int cls = i >> 6, cc = i & 63;
    float v = (part[0][cls][cc]+part[1][cls][cc]+part[2][cls][cc]+part[3][cls][cc]) * SCALE_;
    int cg = c0 + cc;
    float a = inv * nw[cg];
    float bbv = nbv[cg] - m*a;
    Eb[((long)b*128 + h*CLS_ + cls)*512 + cg] = f2b(v*a);
    part[0][cls][cc] = v*bbv;
  }
  __syncthreads();
  if(t < CLS_){
    float s = 0.f;
    for(int cc=0; cc<64; ++cc) s += part[0][t][cc];
    pb[((long)b*8 + cch)*G_ + h*CLS_ + t] = s;
  }
  if(cch == 0 && t >= 64 && t < 64 + CLS_){
    int tt = t - 64;
    float bacc = 0.f;
    for(int d=0; d<HD_; ++d) bacc += key[tt][d]*pqb[h*HD_+d];
    ebb[b*G_ + h*CLS_ + tt] = bacc*SCALE_;
  }
}

// amap GEMM + fused fc1 (staging v2: 8-way-max LDS write conflicts, same values)
__global__ __launch_bounds__(256) void k_amap_fc1(const unsigned short* __restrict__ Eb,
                                                  const float* __restrict__ xp,
                                                  const float* __restrict__ ebb,
                                                  const float* __restrict__ pb,
                                                  const unsigned short* __restrict__ w1b,
                                                  const float* __restrict__ f1bias,
                                                  const float* __restrict__ g1, const float* __restrict__ b1,
                                                  float* __restrict__ amapT,
                                                  float* __restrict__ xf, unsigned short* __restrict__ xub,
                                                  float* __restrict__ sq){
  __shared__ unsigned short Xl[64*520];
  __shared__ unsigned short Bgl[4096];
  unsigned short* A1 = Xl;
  int b = blockIdx.y, n0 = blockIdx.x*64;
  int t = threadIdx.x, w = t >> 6, l = t & 63;
  int wr = w >> 1, wc = w & 1;
  {
    // thread owns 4 consecutive n (one float4) for 32 c values.
    // c spacing of 2 within a wave spreads banks: per write instr
    // banks = (nb4&1)*16 + 4j + cs  -> 8 distinct (8-way vs old 16-way).
    int nb4 = t & 15, cs = t >> 4;
    const float* xb = xp + (long)b*C_*N_ + n0 + nb4*4;
#pragma unroll 4
    for(int pass=0; pass<32; ++pass){
      int c = cs*2 + (pass & 1) + (pass >> 1)*32;
      float4 v = *(const float4*)(xb + (long)c*N_);
      int base = (nb4*4)*520 + c;
      Xl[base        ] = f2b(v.x);
      Xl[base + 520  ] = f2b(v.y);
      Xl[base + 1040 ] = f2b(v.z);
      Xl[base + 1560 ] = f2b(v.w);
    }
  }
  __syncthreads();
  f32x4 acc[2][4] = {};
  const unsigned short* Bt = Eb + ((long)b*128 + w*16 + (l>>2))*512 + (l&3)*8;
  int ra = wr*32 + (l & 15);
  int rb = wc*64 + (l & 15);
  int kq = (l >> 4) * 8;
  for(int k0 = 0; k0 < 512; k0 += 32){
    if(k0) __syncthreads();
    GLOAD16(Bt + k0,          &Bgl[w*512]);
    GLOAD16(Bt + 64*512 + k0, &Bgl[2048 + w*512]);
    __syncthreads();
    bf16x8 af[2], bfr[4];
#pragma unroll
    for(int rt=0; rt<2; ++rt) af[rt]  = *(const bf16x8*)&Xl[(ra + rt*16)*520 + k0 + kq];
#pragma unroll
    for(int ct=0; ct<4; ++ct) bfr[ct] = *(const bf16x8*)&Bgl[(rb + ct*16)*32 + kq];
#pragma unroll
    for(int rt=0; rt<2; ++rt)
#pragma unroll
      for(int ct=0; ct<4; ++ct)
        acc[rt][ct] = __builtin_amdgcn_mfma_f32_16x16x32_bf16(af[rt], bfr[ct], acc[rt][ct], 0, 0, 0);
  }
  float bias4[4];
#pragma unroll
  for(int ct=0; ct<4; ++ct){
    int g = wc*64 + ct*16 + (l & 15);
    float bi = 0.f;
    if(g < G_){
      bi = ebb[b*G_ + g];
#pragma unroll
      for(int cc=0; cc<8; ++cc) bi += pb[((long)b*8 + cc)*G_ + g];
    }
    bias4[ct] = bi;
  }
  __syncthreads();
  int r0 = (l >> 4)*4;
#pragma unroll
  for(int rt=0; rt<2; ++rt){
#pragma unroll
    for(int r=0; r<4; ++r){
      int lrow = wr*32 + rt*16 + r0 + r;
      long rowb = ((long)b*N_ + n0 + lrow)*G_;
#pragma unroll
      for(int ct=0; ct<4; ++ct){
        int g = wc*64 + ct*16 + (l & 15);
        if(g < G_){
          float val = acc[rt][ct][r] + bias4[ct];
          amapT[rowb + g] = val;
          A1[lrow*96 + g] = f2b(val);
        } else if(g < 96){
          A1[lrow*96 + g] = 0;
        }
      }
    }
  }
  __syncthreads();
  int lr = l & 15, lk = l >> 4;
  bf16x8 ay[3];
  const unsigned short* arow = &A1[(w*16 + lr)*96 + lk*8];
#pragma unroll
  for(int ks=0; ks<3; ++ks) ay[ks] = *(const bf16x8*)&arow[ks*32];
  f32x4 acc5[5] = {};
  const unsigned short* wrow = w1b + (long)lr*96 + lk*8;
#pragma unroll
  for(int ks=0; ks<3; ++ks){
#pragma unroll
    for(int ct=0; ct<5; ++ct){
      bf16x8 bw = *(const bf16x8*)&wrow[ct*16*96 + ks*32];
      acc5[ct] = __builtin_amdgcn_mfma_f32_16x16x32_bf16(ay[ks], bw, acc5[ct], 0, 0, 0);
    }
  }
  float v[5][4];
  float ssq[4] = {0.f,0.f,0.f,0.f};
#pragma unroll
  for(int ct=0; ct<5; ++ct){
    int o = ct*16 + lr;
    float bi = f1bias[o], ga = g1[o]*BNS_, bb = b1[o];
#pragma unroll
    for(int i=0;i<4;++i){
      float vv = (acc5[ct][i] + bi)*ga + bb;
      v[ct][i] = vv;
      ssq[i] += vv*vv;
    }
  }
#pragma unroll
  for(int d=1; d<16; d<<=1){
#pragma unroll
    for(int i=0;i<4;++i) ssq[i] += __shfl_xor(ssq[i], d);
  }
  long row0g = (long)b*N_ + n0 + w*16;
#pragma unroll
  for(int i=0;i<4;++i){
    long row = row0g + lk*4 + i;
    float invn = 1.0f / fmaxf(sqrtf(ssq[i]), 1e-12f);
#pragma unroll
    for(int ct=0; ct<5; ++ct){
      int o = ct*16 + lr;
      xf[row*G_ + o] = v[ct][i];
      xub[row*96 + o] = f2b(v[ct][i]*invn);
    }
    xub[row*96 + 80 + lr] = 0;
    if(lr == 0) sq[row] = ssq[i]*invn*invn;
  }
}

// MFMA GEMM: Out[b][o][n] = sum_c Wb[o][c]*Xb[b][n][c] + bias[o] (+Res)
template<bool RES>
__global__ __launch_bounds__(256) void k_gemm_mfma(const unsigned short* __restrict__ Wb,
                                                   const unsigned short* __restrict__ Xb,
                                                   const float* __restrict__ bias,
                                                   const float* __restrict__ Res,
                                                   float* __restrict__ Out){
  __shared__ unsigned short Al[4096];
  __shared__ unsigned short Bl[4096];
  int b = blockIdx.z;
  int o0 = blockIdx.y*128, n0 = blockIdx.x*128;
  int t = threadIdx.x, w = t >> 6, l = t & 63;
  int wr = w >> 1, wc = w & 1;
  f32x4 acc[4][4] = {};
  const unsigned short* Wt = Wb + (long)(o0 + w*16 + (l>>2))*512 + (l&3)*8;
  const unsigned short* Xt = Xb + ((long)b*N_ + n0 + w*16 + (l>>2))*512 + (l&3)*8;
  int ra = wr*64 + (l & 15);
  int rb = wc*64 + (l & 15);
  int kq = (l >> 4) * 8;
  for(int k0 = 0; k0 < 512; k0 += 32){
    if(k0) __syncthreads();
    GLOAD16(Wt + k0,            &Al[w*512]);
    GLOAD16(Wt + 64*512 + k0,   &Al[2048 + w*512]);
    GLOAD16(Xt + k0,            &Bl[w*512]);
    GLOAD16(Xt + 64*512 + k0,   &Bl[2048 + w*512]);
    __syncthreads();
    bf16x8 af[4], bfr[4];
#pragma unroll
    for(int i=0;i<4;++i){
      af[i]  = *(const bf16x8*)&Al[(ra + i*16)*32 + kq];
      bfr[i] = *(const bf16x8*)&Bl[(rb + i*16)*32 + kq];
    }
#pragma unroll
    for(int mi=0; mi<4; ++mi)
#pragma unroll
      for(int ni=0; ni<4; ++ni)
        acc[mi][ni] = __builtin_amdgcn_mfma_f32_16x16x32_bf16(af[mi], bfr[ni], acc[mi][ni], 0, 0, 0);
  }
  long obase = ((long)b*C_ + o0 + wr*64)*N_ + n0 + wc*64 + (l & 15);
  int r0 = (l >> 4) * 4;
#pragma unroll
  for(int mi=0; mi<4; ++mi){
#pragma unroll
    for(int r=0; r<4; ++r){
      int row = mi*16 + r0 + r;
      float bi = bias[o0 + wr*64 + row];
#pragma unroll
      for(int ni=0; ni<4; ++ni){
        long oi = obase + (long)row*N_ + ni*16;
        float v = acc[mi][ni][r] + bi;
        if(RES) v += Res[oi];
        Out[oi] = v;
      }
    }
  }
}

// neg_d via bf16 MFMA
__global__ __launch_bounds__(256) void k_negd_mfma(const unsigned short* __restrict__ xub,
                                                   const float* __restrict__ sq,
                                                   float* __restrict__ negd){
  __shared__ unsigned short Al[128*96];
  __shared__ unsigned short Bl[128*96];
  int b = blockIdx.z;
  int n0 = blockIdx.y*128, m0 = blockIdx.x*128;
  int t = threadIdx.x, w = t >> 6, l = t & 63;
  int wr = w >> 1, wc = w & 1;
  const unsigned short* gA = xub + ((long)b*N_ + n0)*96;
  const unsigned short* gB = xub + ((long)b*N_ + m0)*96;
#pragma unroll
  for(int rd=0; rd<6; ++rd){
    int chunk = rd*4 + w;
    GLOAD16(gA + chunk*512 + l*8, &Al[chunk*512]);
    GLOAD16(gB + chunk*512 + l*8, &Bl[chunk*512]);
  }
  __syncthreads();
  f32x4 acc[4][4] = {};
  int ra = wr*64 + (l & 15);
  int rb = wc*64 + (l & 15);
#pragma unroll
  for(int ks=0; ks<3; ++ks){
    int kq = ks*32 + (l >> 4)*8;
    bf16x8 af[4], bfr[4];
#pragma unroll
    for(int i=0;i<4;++i){
      af[i]  = *(const bf16x8*)&Al[(ra + i*16)*96 + kq];
      bfr[i] = *(const bf16x8*)&Bl[(rb + i*16)*96 + kq];
    }
#pragma unroll
    for(int mi=0; mi<4; ++mi)
#pragma unroll
      for(int ni=0; ni<4; ++ni)
        acc[mi][ni] = __builtin_amdgcn_mfma_f32_16x16x32_bf16(af[mi], bfr[ni], acc[mi][ni], 0, 0, 0);
  }
  int r0 = (l >> 4)*4;
  const float* sqb = sq + (long)b*N_;
#pragma unroll
  for(int mi=0; mi<4; ++mi){
#pragma unroll
    for(int r=0; r<4; ++r){
      int n = n0 + wr*64 + mi*16 + r0 + r;
      float sn = sqb[n];
      long row = ((long)b*N_ + n)*N_;
#pragma unroll
      for(int ni=0; ni<4; ++ni){
        int m = m0 + wc*64 + ni*16 + (l & 15);
        negd[row + m] = 2.f*acc[mi][ni][r] - sn - sqb[m];
      }
    }
  }
}

// top-9 per row then gather neighbor-max -> y bf16. one wave per row. float4 negd reads.
__global__ __launch_bounds__(256) void k_topk_y(const float* __restrict__ negd, const float* __restrict__ xf,
                                                unsigned short* __restrict__ y){
  int t = threadIdx.x, wv = t >> 6, l = t & 63;
  long r = (long)blockIdx.x*4 + wv;
  long b = r >> 10;
  const float4* row4 = (const float4*)(negd + r*N_);
  float vals[16];
#pragma unroll
  for(int cq=0; cq<4; ++cq){
    float4 v = row4[cq*64 + l];
    vals[cq*4]   = v.x;
    vals[cq*4+1] = v.y;
    vals[cq*4+2] = v.z;
    vals[cq*4+3] = v.w;
  }
  // index of vals[j] = (j>>2)*256 + 4*l + (j&3)  — monotonic in j per lane
  int nbs[K_];
#pragma unroll
  for(int p=0; p<K_; ++p){
    float bv = vals[0]; int bj = 0;
#pragma unroll
    for(int j=1;j<16;++j) if(vals[j] > bv){ bv = vals[j]; bj = j; }
    int bm = (bj >> 2)*256 + 4*l + (bj & 3);
#pragma unroll
    for(int d=1; d<64; d<<=1){
      float ov = __shfl_xor(bv, d);
      int   om = __shfl_xor(bm, d);
      if(ov > bv || (ov == bv && om < bm)){ bv = ov; bm = om; }
    }
    nbs[p] = bm;
#pragma unroll
    for(int j=0;j<16;++j) if(bm == (j >> 2)*256 + 4*l + (j & 3)) vals[j] = -INFINITY;
  }
  const float* frow = xf + r*G_;
  int o2s = (l < 16) ? (64 + l) : 0;
  float f0 = frow[l];
  float f1 = frow[o2s];
  float m0 = -INFINITY, m1 = -INFINITY;
#pragma unroll
  for(int k=0;k<K_;++k){
    const float* nr = xf + ((long)b*N_ + nbs[k])*G_;
    m0 = fmaxf(m0, nr[l]);
    m1 = fmaxf(m1, nr[o2s]);
  }
  unsigned short* yr = y + r*G2_;
  ushort2 u0; u0.x = f2b(f0); u0.y = f2b(m0 - f0);
  *(ushort2*)&yr[2*l] = u0;
  if(l < 16){
    ushort2 u1; u1.x = f2b(f1); u1.y = f2b(m1 - f1);
    *(ushort2*)&yr[128 + 2*l] = u1;
  }
}

// MFMA mixer + bn2 + gelu + fc2 + bn3 + amap -> goutT
__global__ __launch_bounds__(256) void k_mixer_mfma(const unsigned short* __restrict__ y,
                                                    const unsigned short* __restrict__ w1bd,
                                                    const float* __restrict__ mrb,
                                                    const float* __restrict__ g2, const float* __restrict__ b2,
                                                    const unsigned short* __restrict__ fc2b16,
                                                    const float* __restrict__ fc2bias,
                                                    const float* __restrict__ g3, const float* __restrict__ b3,
                                                    const float* __restrict__ amapT, float* __restrict__ goutT){
  __shared__ unsigned short zl[4][16][G2_];
  int t = threadIdx.x, w = t >> 6, l = t & 63;
  long row0 = ((long)blockIdx.x*4 + w)*16;
  int lr = l & 15, lk = l >> 4;
  bf16x8 ay[5];
  const unsigned short* yrow = y + (row0 + lr)*G2_ + lk*8;
#pragma unroll
  for(int ks=0; ks<5; ++ks) ay[ks] = *(const bf16x8*)&yrow[ks*32];
  f32x4 accz[10] = {};
  const unsigned short* wb = w1bd + (long)lr*G2_ + lk*8;
#pragma unroll
  for(int ks=0; ks<5; ++ks){
#pragma unroll
    for(int ct=0; ct<10; ++ct){
      bf16x8 bw = *(const bf16x8*)&wb[ct*16*G2_ + ks*32];
      accz[ct] = __builtin_amdgcn_mfma_f32_16x16x32_bf16(ay[ks], bw, accz[ct], 0, 0, 0);
    }
  }
#pragma unroll
  for(int ct=0; ct<10; ++ct){
    int o = ct*16 + lr;
    float bi = mrb[o], ga = g2[o]*BNS_, bb = b2[o];
#pragma unroll
    for(int i=0;i<4;++i){
      float v = (accz[ct][i] + bi)*ga + bb;
      float zz = v * 0.5f * (1.0f + erff(v * INVSQRT2_));
      zl[w][lk*4 + i][o] = f2b(zz);
    }
  }
  __syncthreads();
  bf16x8 az[5];
#pragma unroll
  for(int ks=0; ks<5; ++ks) az[ks] = *(const bf16x8*)&zl[w][lr][ks*32 + lk*8];
  f32x4 acc2[5] = {};
  const unsigned short* fb = fc2b16 + (long)lr*G2_ + lk*8;
#pragma unroll
  for(int ks=0; ks<5; ++ks){
#pragma unroll
    for(int ct=0; ct<5; ++ct){
      bf16x8 bw = *(const bf16x8*)&fb[ct*16*G2_ + ks*32];
      acc2[ct] = __builtin_amdgcn_mfma_f32_16x16x32_bf16(az[ks], bw, acc2[ct], 0, 0, 0);
    }
  }
#pragma unroll
  for(int ct=0; ct<5; ++ct){
    int o = ct*16 + lr;
    float bi = fc2bias[o], ga = g3[o]*BNS_, bb = b3[o];
#pragma unroll
    for(int i=0;i<4;++i){
      long row = row0 + lk*4 + i;
      float v = (acc2[ct][i] + bi)*ga + bb + amapT[row*G_ + o];
      goutT[row*G_ + o] = v;
    }
  }
}

// per-thread softmax + MFMA PV -> bf16 aob[b][n][c]
__global__ __launch_bounds__(256) void k_softmax_pv(const float* __restrict__ goutT, const float* __restrict__ kv,
                                                    unsigned short* __restrict__ aob){
  int bh = blockIdx.x; int b = bh >> 2, h = bh & 3;
  int n0 = blockIdx.y * 64;
  __shared__ unsigned short Vt[128*32];
  __shared__ unsigned short Pl[64*40];
  __shared__ unsigned short Os[64*132];
  int t = threadIdx.x, w = t >> 6, l = t & 63;
  if(t < 128){
    int d = t;
    const float* vb = kv + ((long)b*CLS_)*1024 + C_ + h*HD_ + d;
#pragma unroll
    for(int cls=0; cls<CLS_; ++cls) Vt[d*32+cls] = f2b(vb[(long)cls*1024]);
#pragma unroll
    for(int cls=CLS_; cls<32; ++cls) Vt[d*32+cls] = 0;
  }
  if(t < 64){
    int n = n0 + t;
    const float* gr = goutT + ((long)b*N_ + n)*G_ + h*CLS_;
    float x[CLS_];
    float mx = -INFINITY;
#pragma unroll
    for(int cls=0; cls<CLS_; ++cls){ x[cls] = gr[cls]; mx = fmaxf(mx, x[cls]); }
    float s = 0.f;
#pragma unroll
    for(int cls=0; cls<CLS_; ++cls){ x[cls] = expf(x[cls]-mx); s += x[cls]; }
    float inv = 1.0f / s;
#pragma unroll
    for(int cls=0; cls<CLS_; ++cls) Pl[t*40+cls] = f2b(x[cls]*inv);
#pragma unroll
    for(int cls=CLS_; cls<32; ++cls) Pl[t*40+cls] = 0;
  }
  __syncthreads();
  int lr = l & 15, kq = (l >> 4)*8;
  f32x4 acc[4][2] = {};
  bf16x8 af[4], bf2[2];
#pragma unroll
  for(int rt=0; rt<4; ++rt) af[rt] = *(const bf16x8*)&Pl[(rt*16+lr)*40 + kq];
#pragma unroll
  for(int ci=0; ci<2; ++ci) bf2[ci] = *(const bf16x8*)&Vt[((2*w+ci)*16+lr)*32 + kq];
#pragma unroll
  for(int rt=0; rt<4; ++rt)
#pragma unroll
    for(int ci=0; ci<2; ++ci)
      acc[rt][ci] = __builtin_amdgcn_mfma_f32_16x16x32_bf16(af[rt], bf2[ci], acc[rt][ci], 0, 0, 0);
  int r0 = (l >> 4)*4;
#pragma unroll
  for(int rt=0; rt<4; ++rt)
#pragma unroll
    for(int ci=0; ci<2; ++ci)
#pragma unroll
      for(int i=0; i<4; ++i)
        Os[(rt*16 + r0 + i)*132 + (2*w+ci)*16 + lr] = f2b(acc[rt][ci][i]);
  __syncthreads();
  unsigned short* ob = aob + ((long)b*N_ + n0)*C_ + h*HD_;
#pragma unroll
  for(int j=0; j<8; ++j){
    int idx = t + 256*j;
    int row = idx >> 5, ch = idx & 31;
    *(ushort4*)&ob[(long)row*C_ + ch*4] =
        *(const ushort4*)&Os[row*132 + ch*4];
  }
}

extern "C" void kernel_launch(void* const* d_in, const int* in_sizes, int n_in,
                              void* d_out, int out_size, void* d_ws, size_t ws_size,
                              hipStream_t stream){
  const float* x_cls   = (const float*)d_in[0];
  const float* x_patch = (const float*)d_in[1];
  const float* norm_x_w = (const float*)d_in[2];
  const float* norm_x_b = (const float*)d_in[3];
  const float* pq_w  = (const float*)d_in[4];
  const float* pq_b  = (const float*)d_in[5];
  const float* ncls_w = (const float*)d_in[6];
  const float* ncls_b = (const float*)d_in[7];
  const float* pkv_w = (const float*)d_in[8];
  const float* pkv_b = (const float*)d_in[9];
  const float* fc1_w = (const float*)d_in[10];
  const float* fc1_b = (const float*)d_in[11];
  const float* bn1_g = (const float*)d_in[12];
  const float* bn1_b = (const float*)d_in[13];
  const float* mr_w  = (const float*)d_in[14];
  const float* mr_b  = (const float*)d_in[15];
  const float* bn2_g = (const float*)d_in[16];
  const float* bn2_b = (const float*)d_in[17];
  const float* fc2_w = (const float*)d_in[18];
  const float* fc2_b = (const float*)d_in[19];
  const float* bn3_g = (const float*)d_in[20];
  const float* bn3_b = (const float*)d_in[21];
  const float* proj_w = (const float*)d_in[22];
  const float* proj_b = (const float*)d_in[23];

  float* ws = (float*)d_ws;
  float* part   = ws + OFF_PART;
  float* ebb    = ws + OFF_EBB;
  float* kvbuf  = ws + OFF_KV;
  float* amapT  = ws + OFF_AMAPT;
  float* xf     = ws + OFF_XF;
  float* sqbuf  = ws + OFF_SQ;
  float* negd   = ws + OFF_NEGD;
  float* goutT  = ws + OFF_GOUTT;
  float* pbuf   = ws + OFF_PB;
  unsigned short* Eb     = (unsigned short*)(ws + OFF_EB);
  unsigned short* xub    = (unsigned short*)(ws + OFF_XUB);
  unsigned short* w1bd   = (unsigned short*)(ws + OFF_W1BD);
  unsigned short* fc2b16 = (unsigned short*)(ws + OFF_FC2B);
  unsigned short* ybuf   = (unsigned short*)(ws + OFF_Y);
  unsigned short* fc1b16 = (unsigned short*)(ws + OFF_FC1B);
  unsigned short* xcb    = (unsigned short*)(ws + OFF_XCB);
  unsigned short* pkvb16 = (unsigned short*)(ws + OFF_PKVB);
  unsigned short* aob = (unsigned short*)(ws + OFF_NEGD);   // overlay: negd dead after topk_y
  unsigned short* wpb = (unsigned short*)(ws + OFF_WPB);
  float* out = (float*)d_out;

  k_pre<<<2128, 256, 0, stream>>>(x_patch, part, x_cls, ncls_w, ncls_b, xcb,
                                  pkv_w, pkvb16, proj_w, wpb,
                                  mr_w, fc2_w, fc1_w, w1bd, fc2b16, fc1b16);
  k_kv_mfma<<<128, 256, 0, stream>>>(xcb, pkvb16, pkv_b, kvbuf);
  k_eprep<<<dim3(16,5,8), 256, 0, stream>>>(kvbuf, pq_w, pq_b, part, norm_x_w, norm_x_b, Eb, ebb, pbuf);
  k_amap_fc1<<<dim3(16,16), 256, 0, stream>>>(Eb, x_patch, ebb, pbuf, fc1b16, fc1_b, bn1_g, bn1_b,
                                              amapT, xf, xub, sqbuf);
  k_negd_mfma<<<dim3(8,8,16), 256, 0, stream>>>(xub, sqbuf, negd);
  k_topk_y<<<4096, 256, 0, stream>>>(negd, xf, ybuf);
  k_mixer_mfma<<<256, 256, 0, stream>>>(ybuf, w1bd, mr_b, bn2_g, bn2_b,
                                        fc2b16, fc2_b, bn3_g, bn3_b, amapT, goutT);
  k_softmax_pv<<<dim3(64,16), 256, 0, stream>>>(goutT, kvbuf, aob);
  k_gemm_mfma<true><<<dim3(8,4,16), 256, 0, stream>>>(wpb, aob, proj_b, x_patch, out);
}